// Round 11
// baseline (350.577 us; speedup 1.0000x reference)
//
#include <hip/hip_runtime.h>
#include <stdint.h>

// TopoLoss: approximate persistence-diagram Wasserstein loss.
// Round 10: two-kernel pipeline. K1 (topo_scan): max-occupancy streaming stencil,
// extrema keys appended to per-image-type global lists (wave-aggregated atomics).
// K2 (topo_sel): per-image radix-select from L2-resident lists with lane-privatized
// bank-skewed MSB histograms + register bitonic sort. Order statistics bit-exact.

#define KPTS 128
#define BIGF 1.0e9f
#define IMG_W 256
#define NPIX (IMG_W * IMG_W)
#define NTH 1024
#define QITERS (NPIX / 4 / NTH)   // 16 (fallback kernels)
#define LCAP 16384                // >= per-type extrema count (~13.1K)
#define HPAD 264                  // histogram copy stride (bank-skew: 264%32=8)

__device__ __forceinline__ uint32_t f2key(float f) {
    uint32_t u = __float_as_uint(f);
    return (u & 0x80000000u) ? ~u : (u | 0x80000000u);
}
__device__ __forceinline__ float key2f(uint32_t k) {
    uint32_t u = (k & 0x80000000u) ? (k ^ 0x80000000u) : ~k;
    return __uint_as_float(u);
}

// buf layout: 0=b0 (min,low,asc) 1=d0 (max,low,asc) 2=b1 (max,high,desc) 3=d1 (min,high,desc)

// ---------------- K1: streaming stencil + global list append ----------------
__global__ __launch_bounds__(256) void topo_scan_kernel(
        const float* __restrict__ X, const float* __restrict__ Y,
        uint32_t* __restrict__ gkeys, uint32_t* __restrict__ gcnt, int B) {
    const int tid = threadIdx.x;
    const int lane = tid & 63;
    const int wv = tid >> 6;                 // 4 waves/block
    const int gw = blockIdx.x * 4 + wv;      // global wave id
    const int nw = gridDim.x * 4;
    const int totalRows = 2 * B * IMG_W;
    const unsigned long long ltm = (1ull << lane) - 1ull;

    for (int r = gw; r < totalRows; r += nw) {
        int im = r >> 8, row = r & 255;
        const float* base = ((im & 1) ? Y : X) + (size_t)(im >> 1) * NPIX + (size_t)row * IMG_W;
        float4 cur = *(const float4*)(base + lane * 4);
        bool hu = row > 0, hd = row < (IMG_W - 1);
        float4 up = cur, dn = cur;
        if (hu) up = *(const float4*)(base - IMG_W + lane * 4);
        if (hd) dn = *(const float4*)(base + IMG_W + lane * 4);
        float lft = __shfl_up(cur.w, 1);
        float rgt = __shfl_down(cur.x, 1);
        bool hl = (lane > 0), hr = (lane < 63);
        float cv[4] = {cur.x, cur.y, cur.z, cur.w};
        float uv[4] = {up.x, up.y, up.z, up.w};
        float dv[4] = {dn.x, dn.y, dn.z, dn.w};
        bool mnf[4], mxf[4];
        uint32_t kk[4];
        #pragma unroll
        for (int j = 0; j < 4; ++j) {
            float v = cv[j];
            bool el = (j > 0) || hl, er = (j < 3) || hr;
            float vl = (j > 0) ? cv[j - 1] : lft;
            float vr = (j < 3) ? cv[j + 1] : rgt;
            float nmn = fminf(fminf(el ? vl : BIGF, er ? vr : BIGF),
                              fminf(hu ? uv[j] : BIGF, hd ? dv[j] : BIGF));
            float nmx = fmaxf(fmaxf(el ? vl : -BIGF, er ? vr : -BIGF),
                              fmaxf(hu ? uv[j] : -BIGF, hd ? dv[j] : -BIGF));
            mnf[j] = (v <= nmn);
            mxf[j] = (v >= nmx);
            kk[j] = f2key(v);
        }
        #pragma unroll
        for (int t = 0; t < 2; ++t) {
            bool f0 = t ? mxf[0] : mnf[0], f1 = t ? mxf[1] : mnf[1];
            bool f2 = t ? mxf[2] : mnf[2], f3 = t ? mxf[3] : mnf[3];
            unsigned long long m0 = __ballot(f0), m1 = __ballot(f1),
                               m2 = __ballot(f2), m3 = __ballot(f3);
            uint32_t c0 = (uint32_t)__popcll(m0), c1 = (uint32_t)__popcll(m1),
                     c2 = (uint32_t)__popcll(m2), c3 = (uint32_t)__popcll(m3);
            uint32_t bse = 0;
            if (lane == 0) bse = atomicAdd(&gcnt[im * 2 + t], c0 + c1 + c2 + c3);
            bse = __shfl(bse, 0);
            uint32_t* dst = gkeys + (size_t)(im * 2 + t) * LCAP;
            uint32_t o;
            if (f0) { o = bse + (uint32_t)__popcll(m0 & ltm);                dst[o < LCAP ? o : LCAP - 1] = kk[0]; }
            if (f1) { o = bse + c0 + (uint32_t)__popcll(m1 & ltm);           dst[o < LCAP ? o : LCAP - 1] = kk[1]; }
            if (f2) { o = bse + c0 + c1 + (uint32_t)__popcll(m2 & ltm);      dst[o < LCAP ? o : LCAP - 1] = kk[2]; }
            if (f3) { o = bse + c0 + c1 + c2 + (uint32_t)__popcll(m3 & ltm); dst[o < LCAP ? o : LCAP - 1] = kk[3]; }
        }
    }
}

// ---------------- K2: per-image radix select + register sort ----------------
struct SMQ {
    uint32_t keys[LCAP];      // 64 KB
    uint32_t h8[8 * HPAD];    // 8.25 KB (skewed copies)
    uint32_t pref[2], rank[2], ccnt[2];
    int      flagAll[2];
    float    buf[4][KPTS];    // 2 KB
};                            // ~74.5 KB -> 2 blocks/CU

// wave-parallel: pick bin containing rank r; h has ncop copies at HPAD stride.
__device__ __forceinline__ void binSelP(const uint32_t* h, int ncop, int lane, uint32_t r,
                                        uint32_t& bsel, uint32_t& newr) {
    uint32_t b0 = 0, b1 = 0, b2 = 0, b3 = 0;
    for (int c = 0; c < ncop; ++c) {
        const uint32_t* hh = h + c * HPAD;
        b0 += hh[4 * lane];     b1 += hh[4 * lane + 1];
        b2 += hh[4 * lane + 2]; b3 += hh[4 * lane + 3];
    }
    uint32_t s4 = b0 + b1 + b2 + b3, cum = s4;
    #pragma unroll
    for (int d = 1; d < 64; d <<= 1) { uint32_t t = __shfl_up(cum, d); if (lane >= d) cum += t; }
    unsigned long long m = __ballot(cum > r);
    int L = (m == 0ull) ? 63 : __builtin_ctzll(m);
    uint32_t cumL = __shfl(cum, L), s4L = __shfl(s4, L);
    uint32_t a0 = __shfl(b0, L), a1 = __shfl(b1, L), a2 = __shfl(b2, L);
    uint32_t excl = cumL - s4L;
    if (excl + a0 > r)                { bsel = 4u * L;     newr = r - excl; }
    else if (excl + a0 + a1 > r)      { bsel = 4u * L + 1; newr = r - excl - a0; }
    else if (excl + a0 + a1 + a2 > r) { bsel = 4u * L + 2; newr = r - excl - a0 - a1; }
    else                              { bsel = 4u * L + 3; newr = r - excl - a0 - a1 - a2; }
}

// 128-element bitonic sort in registers, one wave, 2 elems/lane.
__device__ __forceinline__ void waveSort128(float e[2], bool asc, int lane) {
    for (int size = 2; size <= 128; size <<= 1) {
        for (int stride = size >> 1; stride > 0; stride >>= 1) {
            if (stride == 64) {
                float a = e[0], b = e[1];
                e[0] = asc ? fminf(a, b) : fmaxf(a, b);
                e[1] = asc ? fmaxf(a, b) : fminf(a, b);
            } else {
                #pragma unroll
                for (int r = 0; r < 2; ++r) {
                    int i = r * 64 + lane;
                    float v = e[r];
                    float w = __shfl_xor(v, stride);
                    bool up = ((i & size) == 0) ? asc : !asc;
                    bool lower = (i & stride) == 0;
                    float mn = fminf(v, w), mx = fmaxf(v, w);
                    e[r] = (lower == up) ? mn : mx;
                }
            }
        }
    }
}

__global__ __launch_bounds__(NTH, 8) void topo_sel_kernel(
        const uint32_t* __restrict__ gkeys, const uint32_t* __restrict__ gcnt,
        float* __restrict__ diagOut, int B) {
    __shared__ SMQ sm;
    const int tid = threadIdx.x;
    const int lane = tid & 63;
    const int wv = tid >> 6;
    const int im = blockIdx.x;
    const int hc = lane & 7;

    for (int ph = 0; ph < 2; ++ph) {   // 0: minima -> {b0,d1}; 1: maxima -> {d0,b1}
        for (int i = tid; i < 8 * HPAD; i += NTH) sm.h8[i] = 0u;
        __syncthreads();
        const uint32_t* list = gkeys + (size_t)(im * 2 + ph) * LCAP;
        uint32_t C = gcnt[im * 2 + ph]; if (C > LCAP) C = LCAP;

        // copy list to LDS + lane-privatized skewed MSB histogram
        for (uint32_t i = tid; i < C; i += NTH) {
            uint32_t k = list[i];
            sm.keys[i] = k;
            atomicAdd(&sm.h8[hc * HPAD + (k >> 24)], 1u);
        }
        __syncthreads();

        // top-level select: wave0 = low sel, wave1 = high sel
        if (wv < 2) {
            bool low = (wv == 0);
            if (C < KPTS) {
                if (lane == 0) { sm.flagAll[wv] = 1; sm.pref[wv] = 0u; sm.rank[wv] = 0u; }
            } else {
                uint32_t bsel, nr;
                binSelP(sm.h8, 8, lane, low ? (KPTS - 1) : (C - KPTS), bsel, nr);
                if (lane == 0) { sm.flagAll[wv] = 0; sm.pref[wv] = bsel; sm.rank[wv] = nr; }
            }
        }
        __syncthreads();

        // levels 2..0: prefix-filtered LDS list scans (copies 0,1 of h8)
        for (int lvl = 2; lvl >= 0; --lvl) {
            for (int i = tid; i < 2 * HPAD; i += NTH) sm.h8[i] = 0u;
            __syncthreads();
            int f0 = sm.flagAll[0], f1 = sm.flagAll[1];
            uint32_t p0 = sm.pref[0], p1 = sm.pref[1];
            const int sp = 8 * (lvl + 1), sb = 8 * lvl;
            for (uint32_t i = tid; i < C; i += NTH) {
                uint32_t k = sm.keys[i], hi = k >> sp, by = (k >> sb) & 255u;
                if (!f0 && hi == p0) atomicAdd(&sm.h8[by], 1u);
                if (!f1 && hi == p1) atomicAdd(&sm.h8[HPAD + by], 1u);
            }
            __syncthreads();
            if (wv < 2 && !sm.flagAll[wv]) {
                uint32_t bsel, nr;
                binSelP(&sm.h8[wv * HPAD], 1, lane, sm.rank[wv], bsel, nr);
                if (lane == 0) { sm.pref[wv] = (sm.pref[wv] << 8) | bsel; sm.rank[wv] = nr; }
            }
            __syncthreads();
        }

        // collect strict winners, tie/sentinel pad
        if (tid < 2) sm.ccnt[tid] = 0u;
        __syncthreads();
        const int g0 = (ph == 0) ? 0 : 1;
        const int g1 = (ph == 0) ? 3 : 2;
        {
            int f0 = sm.flagAll[0], f1 = sm.flagAll[1];
            uint32_t t0 = sm.pref[0], t1 = sm.pref[1];
            for (uint32_t i = tid; i < C; i += NTH) {
                uint32_t k = sm.keys[i];
                if (f0 || k < t0) { uint32_t s = atomicAdd(&sm.ccnt[0], 1u); if (s < KPTS) sm.buf[g0][s] = key2f(k); }
                if (f1 || k > t1) { uint32_t s = atomicAdd(&sm.ccnt[1], 1u); if (s < KPTS) sm.buf[g1][s] = key2f(k); }
            }
        }
        __syncthreads();
        if (tid < 2 * KPTS) {
            int l = tid >> 7, i = tid & 127;
            int g = (l == 0) ? g0 : g1;
            if ((uint32_t)i >= sm.ccnt[l])
                sm.buf[g][i] = sm.flagAll[l] ? ((l == 0) ? BIGF : -BIGF) : key2f(sm.pref[l]);
        }
        __syncthreads();
    }

    // 4 register-resident 128-elem bitonic sorts (waves 0..3, no barriers)
    if (wv < 4) {
        float e[2];
        e[0] = sm.buf[wv][lane];
        e[1] = sm.buf[wv][lane + 64];
        waveSort128(e, wv < 2, lane);
        diagOut[(size_t)im * 512 + wv * 128 + lane]      = e[0];
        diagOut[(size_t)im * 512 + wv * 128 + 64 + lane] = e[1];
    }
}

// ---------------- loss + reduce ----------------
__global__ __launch_bounds__(128) void topo_loss_kernel(
        const float* __restrict__ diag, float* __restrict__ lossOut, int B) {
    const int s = blockIdx.x, i = threadIdx.x;
    const float* xw = diag + (size_t)(2 * s) * 512;
    const float* yw = xw + 512;
    const float H = 0.5f * BIGF;
    float b0x = xw[i], d0x = xw[128 + i], b1x = xw[256 + i], d1x = xw[384 + i];
    float b0y = yw[i], d0y = yw[128 + i], b1y = yw[256 + i], d1y = yw[384 + i];
    bool vx0 = (b0x < H) && (d0x < H);
    float px0b = vx0 ? b0x : 0.f, px0d = vx0 ? fmaxf(d0x, b0x) : 0.f;
    bool vy0 = (b0y < H) && (d0y < H);
    float py0b = vy0 ? b0y : 0.f, py0d = vy0 ? fmaxf(d0y, b0y) : 0.f;
    bool vx1 = (b1x > -H) && (d1x > -H);
    float px1b = vx1 ? b1x : 0.f, px1d = vx1 ? fminf(d1x, b1x) : 0.f;
    bool vy1 = (b1y > -H) && (d1y > -H);
    float py1b = vy1 ? b1y : 0.f, py1d = vy1 ? fminf(d1y, b1y) : 0.f;
    float e0 = px0b - py0b, e1 = px0d - py0d, e2 = px1b - py1b, e3 = px1d - py1d;
    float total = e0 * e0 + e1 * e1 + e2 * e2 + e3 * e3;
    for (int off = 32; off; off >>= 1) total += __shfl_down(total, off);
    __shared__ float lr[2];
    if ((i & 63) == 0) lr[i >> 6] = total;
    __syncthreads();
    if (i == 0) lossOut[s] = lr[0] + lr[1];
}

__global__ void topo_reduce_kernel(const float* __restrict__ ws, float* __restrict__ out, int B) {
    float v = 0.f;
    for (int i = threadIdx.x; i < B; i += 256) v += ws[i];
    __shared__ float r[4];
    for (int off = 32; off; off >>= 1) v += __shfl_down(v, off);
    if ((threadIdx.x & 63) == 0) r[threadIdx.x >> 6] = v;
    __syncthreads();
    if (threadIdx.x == 0) out[0] = (r[0] + r[1] + r[2] + r[3]) / (float)B;
}

// ================= fallback: round-8/9 fused pd3 kernel =================
struct SMP {
    uint32_t keys[LCAP];
    uint32_t h8[8][256];
    uint32_t cnt[2];
    uint32_t pref[2], rank[2], ccnt[2];
    int      flagAll[2];
    float    buf[4][KPTS];
};

__device__ __forceinline__ void binSelN(const uint32_t (*h)[256], int ncop, int lane, uint32_t r,
                                        uint32_t& bsel, uint32_t& newr) {
    uint32_t b0 = 0, b1 = 0, b2 = 0, b3 = 0;
    for (int c = 0; c < ncop; ++c) {
        b0 += h[c][4 * lane];     b1 += h[c][4 * lane + 1];
        b2 += h[c][4 * lane + 2]; b3 += h[c][4 * lane + 3];
    }
    uint32_t s4 = b0 + b1 + b2 + b3, cum = s4;
    #pragma unroll
    for (int d = 1; d < 64; d <<= 1) { uint32_t t = __shfl_up(cum, d); if (lane >= d) cum += t; }
    unsigned long long m = __ballot(cum > r);
    int L = (m == 0ull) ? 63 : __builtin_ctzll(m);
    uint32_t cumL = __shfl(cum, L), s4L = __shfl(s4, L);
    uint32_t a0 = __shfl(b0, L), a1 = __shfl(b1, L), a2 = __shfl(b2, L);
    uint32_t excl = cumL - s4L;
    if (excl + a0 > r)                { bsel = 4u * L;     newr = r - excl; }
    else if (excl + a0 + a1 > r)      { bsel = 4u * L + 1; newr = r - excl - a0; }
    else if (excl + a0 + a1 + a2 > r) { bsel = 4u * L + 2; newr = r - excl - a0 - a1; }
    else                              { bsel = 4u * L + 3; newr = r - excl - a0 - a1 - a2; }
}

__global__ __launch_bounds__(NTH, 8) void topo_pd3_kernel(
        const float* __restrict__ X, const float* __restrict__ Y,
        float* __restrict__ diagOut, int B) {
    __shared__ SMP sm;
    const int tid = threadIdx.x;
    const int lane = tid & 63;
    const int wv = tid >> 6;
    const int bid = blockIdx.x;
    const float* img = ((bid & 1) ? Y : X) + (size_t)(bid >> 1) * NPIX;
    const unsigned long long ltm = (1ull << lane) - 1ull;

    for (int ph = 0; ph < 2; ++ph) {
        for (int i = tid; i < 8 * 256; i += NTH) ((uint32_t*)sm.h8)[i] = 0u;
        if (tid == 0) sm.cnt[0] = 0u;
        __syncthreads();
        for (int it = 0; it < QITERS; ++it) {
            int q = it * NTH + tid;
            int p = q * 4;
            int row = p >> 8;
            float4 cur = *(const float4*)(img + p);
            bool hu = row > 0, hd = row < (IMG_W - 1);
            float4 up = cur, dn = cur;
            if (hu) up = *(const float4*)(img + p - IMG_W);
            if (hd) dn = *(const float4*)(img + p + IMG_W);
            float lft = __shfl_up(cur.w, 1);
            float rgt = __shfl_down(cur.x, 1);
            bool hl = (lane > 0), hr = (lane < 63);
            float cv[4] = {cur.x, cur.y, cur.z, cur.w};
            float uv[4] = {up.x, up.y, up.z, up.w};
            float dv[4] = {dn.x, dn.y, dn.z, dn.w};
            bool e0, e1, e2, e3;
            if (ph == 0) {
                #define SMIN(J, E, EL, ER, VL, VR)                                        \
                    { float nm = fminf(fminf((EL) ? (VL) : BIGF, (ER) ? (VR) : BIGF),     \
                                       fminf(hu ? uv[J] : BIGF, hd ? dv[J] : BIGF));      \
                      E = (cv[J] <= nm); }
                SMIN(0, e0, hl, true, lft,  cv[1]);
                SMIN(1, e1, true, true, cv[0], cv[2]);
                SMIN(2, e2, true, true, cv[1], cv[3]);
                SMIN(3, e3, true, hr, cv[2], rgt);
                #undef SMIN
            } else {
                #define SMAX(J, E, EL, ER, VL, VR)                                        \
                    { float nx = fmaxf(fmaxf((EL) ? (VL) : -BIGF, (ER) ? (VR) : -BIGF),   \
                                       fmaxf(hu ? uv[J] : -BIGF, hd ? dv[J] : -BIGF));    \
                      E = (cv[J] >= nx); }
                SMAX(0, e0, hl, true, lft,  cv[1]);
                SMAX(1, e1, true, true, cv[0], cv[2]);
                SMAX(2, e2, true, true, cv[1], cv[3]);
                SMAX(3, e3, true, hr, cv[2], rgt);
                #undef SMAX
            }
            uint32_t k0 = f2key(cv[0]), k1 = f2key(cv[1]), k2 = f2key(cv[2]), k3 = f2key(cv[3]);
            unsigned long long m0 = __ballot(e0), m1 = __ballot(e1),
                               m2 = __ballot(e2), m3 = __ballot(e3);
            uint32_t c0 = (uint32_t)__popcll(m0), c1 = (uint32_t)__popcll(m1),
                     c2 = (uint32_t)__popcll(m2), c3 = (uint32_t)__popcll(m3);
            uint32_t base = 0;
            if (lane == 0) base = atomicAdd(&sm.cnt[0], c0 + c1 + c2 + c3);
            base = __shfl(base, 0);
            uint32_t o;
            if (e0) { o = base + (uint32_t)__popcll(m0 & ltm);                sm.keys[o < LCAP ? o : LCAP - 1] = k0; atomicAdd(&sm.h8[wv >> 1][k0 >> 24], 1u); }
            if (e1) { o = base + c0 + (uint32_t)__popcll(m1 & ltm);           sm.keys[o < LCAP ? o : LCAP - 1] = k1; atomicAdd(&sm.h8[wv >> 1][k1 >> 24], 1u); }
            if (e2) { o = base + c0 + c1 + (uint32_t)__popcll(m2 & ltm);      sm.keys[o < LCAP ? o : LCAP - 1] = k2; atomicAdd(&sm.h8[wv >> 1][k2 >> 24], 1u); }
            if (e3) { o = base + c0 + c1 + c2 + (uint32_t)__popcll(m3 & ltm); sm.keys[o < LCAP ? o : LCAP - 1] = k3; atomicAdd(&sm.h8[wv >> 1][k3 >> 24], 1u); }
        }
        __syncthreads();
        uint32_t C = sm.cnt[0]; if (C > LCAP) C = LCAP;

        if (wv < 2) {
            bool low = (wv == 0);
            if (C < KPTS) {
                if (lane == 0) { sm.flagAll[wv] = 1; sm.pref[wv] = 0u; sm.rank[wv] = 0u; }
            } else {
                uint32_t bsel, nr;
                binSelN(sm.h8, 8, lane, low ? (KPTS - 1) : (C - KPTS), bsel, nr);
                if (lane == 0) { sm.flagAll[wv] = 0; sm.pref[wv] = bsel; sm.rank[wv] = nr; }
            }
        }
        __syncthreads();

        for (int lvl = 2; lvl >= 0; --lvl) {
            for (int i = tid; i < 2 * 256; i += NTH) ((uint32_t*)sm.h8)[i] = 0u;
            __syncthreads();
            int f0 = sm.flagAll[0], f1 = sm.flagAll[1];
            uint32_t p0 = sm.pref[0], p1 = sm.pref[1];
            const int sp = 8 * (lvl + 1), sb = 8 * lvl;
            for (uint32_t i = tid; i < C; i += NTH) {
                uint32_t k = sm.keys[i], hi = k >> sp, by = (k >> sb) & 255u;
                if (!f0 && hi == p0) atomicAdd(&sm.h8[0][by], 1u);
                if (!f1 && hi == p1) atomicAdd(&sm.h8[1][by], 1u);
            }
            __syncthreads();
            if (wv < 2 && !sm.flagAll[wv]) {
                uint32_t bsel, nr;
                binSelN((const uint32_t(*)[256])&sm.h8[wv], 1, lane, sm.rank[wv], bsel, nr);
                if (lane == 0) { sm.pref[wv] = (sm.pref[wv] << 8) | bsel; sm.rank[wv] = nr; }
            }
            __syncthreads();
        }

        if (tid < 2) sm.ccnt[tid] = 0u;
        __syncthreads();
        const int g0 = (ph == 0) ? 0 : 1;
        const int g1 = (ph == 0) ? 3 : 2;
        {
            int f0 = sm.flagAll[0], f1 = sm.flagAll[1];
            uint32_t t0 = sm.pref[0], t1 = sm.pref[1];
            for (uint32_t i = tid; i < C; i += NTH) {
                uint32_t k = sm.keys[i];
                if (f0 || k < t0) { uint32_t s = atomicAdd(&sm.ccnt[0], 1u); if (s < KPTS) sm.buf[g0][s] = key2f(k); }
                if (f1 || k > t1) { uint32_t s = atomicAdd(&sm.ccnt[1], 1u); if (s < KPTS) sm.buf[g1][s] = key2f(k); }
            }
        }
        __syncthreads();
        if (tid < 2 * KPTS) {
            int l = tid >> 7, i = tid & 127;
            int g = (l == 0) ? g0 : g1;
            if ((uint32_t)i >= sm.ccnt[l])
                sm.buf[g][i] = sm.flagAll[l] ? ((l == 0) ? BIGF : -BIGF) : key2f(sm.pref[l]);
        }
        __syncthreads();
    }

    if (wv < 4) {
        float e[2];
        e[0] = sm.buf[wv][lane];
        e[1] = sm.buf[wv][lane + 64];
        waveSort128(e, wv < 2, lane);
        diagOut[(size_t)bid * 512 + wv * 128 + lane]      = e[0];
        diagOut[(size_t)bid * 512 + wv * 128 + 64 + lane] = e[1];
    }
}

extern "C" void kernel_launch(void* const* d_in, const int* in_sizes, int n_in,
                              void* d_out, int out_size, void* d_ws, size_t ws_size,
                              hipStream_t stream) {
    const float* X = (const float*)d_in[0];
    const float* Y = (const float*)d_in[1];
    float* out = (float*)d_out;
    const int B = in_sizes[0] / NPIX;   // 256 samples

    size_t diagSz = (size_t)2 * B * 512 * sizeof(float);          // 2 MB
    size_t lossSz = (size_t)B * sizeof(float);
    size_t cntSz  = (size_t)2 * B * 2 * sizeof(uint32_t);         // 4 KB
    size_t keysSz = (size_t)2 * B * 2 * LCAP * sizeof(uint32_t);  // 67 MB

    if (ws_size >= diagSz + lossSz + cntSz + keysSz) {
        float* diag = (float*)d_ws;
        float* lossbuf = (float*)((char*)d_ws + diagSz);
        uint32_t* gcnt = (uint32_t*)((char*)d_ws + diagSz + lossSz);
        uint32_t* gkeys = (uint32_t*)((char*)d_ws + diagSz + lossSz + cntSz);
        hipMemsetAsync(gcnt, 0, cntSz, stream);
        topo_scan_kernel<<<2048, 256, 0, stream>>>(X, Y, gkeys, gcnt, B);
        topo_sel_kernel<<<2 * B, NTH, 0, stream>>>(gkeys, gcnt, diag, B);
        topo_loss_kernel<<<B, 128, 0, stream>>>(diag, lossbuf, B);
        topo_reduce_kernel<<<1, 256, 0, stream>>>(lossbuf, out, B);
    } else if (ws_size >= diagSz + lossSz) {
        float* diag = (float*)d_ws;
        float* lossbuf = (float*)((char*)d_ws + diagSz);
        topo_pd3_kernel<<<2 * B, NTH, 0, stream>>>(X, Y, diag, B);
        topo_loss_kernel<<<B, 128, 0, stream>>>(diag, lossbuf, B);
        topo_reduce_kernel<<<1, 256, 0, stream>>>(lossbuf, out, B);
    } else {
        topo_pd3_kernel<<<2 * B, NTH, 0, stream>>>(X, Y, (float*)d_ws, B);
    }
}

// Round 12
// 122.827 us; speedup vs baseline: 2.8542x; 2.8542x over previous
//
#include <hip/hip_runtime.h>
#include <stdint.h>

// TopoLoss: approximate persistence-diagram Wasserstein loss.
// Round 12: split pipeline, atomic-light scan. K1 (topo_scan2): each wave owns 16
// rows of one image; pass A counts extrema, ONE atomic pair reserves global list
// space, pass B recomputes (L2-hit) and writes keys at known offsets. Zero LDS ->
// full occupancy. K2 (topo_sel): per-image LDS radix-select + register bitonic
// sort (unchanged, proven). Order statistics bit-exact.

#define KPTS 128
#define BIGF 1.0e9f
#define IMG_W 256
#define NPIX (IMG_W * IMG_W)
#define NTH 1024
#define QITERS (NPIX / 4 / NTH)   // fallback kernel
#define LCAP 16384                // >= per-type extrema count (~13.1K)
#define HPAD 264                  // histogram copy stride (bank-skew: 264%32=8)

__device__ __forceinline__ uint32_t f2key(float f) {
    uint32_t u = __float_as_uint(f);
    return (u & 0x80000000u) ? ~u : (u | 0x80000000u);
}
__device__ __forceinline__ float key2f(uint32_t k) {
    uint32_t u = (k & 0x80000000u) ? (k ^ 0x80000000u) : ~k;
    return __uint_as_float(u);
}

// buf layout: 0=b0 (min,low,asc) 1=d0 (max,low,asc) 2=b1 (max,high,desc) 3=d1 (min,high,desc)

// ---- shared stencil: one image row per wave, 4 px/lane, halo via shfl ----
template <bool WANTK>
__device__ __forceinline__ void stencilRow(const float* __restrict__ img, int row, int lane,
                                           bool mnf[4], bool mxf[4], uint32_t kk[4]) {
    const float* base = img + (size_t)row * IMG_W;
    float4 cur = *(const float4*)(base + lane * 4);
    bool hu = row > 0, hd = row < (IMG_W - 1);
    float4 up = cur, dn = cur;
    if (hu) up = *(const float4*)(base - IMG_W + lane * 4);
    if (hd) dn = *(const float4*)(base + IMG_W + lane * 4);
    float lft = __shfl_up(cur.w, 1);
    float rgt = __shfl_down(cur.x, 1);
    bool hl = (lane > 0), hr = (lane < 63);
    float cv[4] = {cur.x, cur.y, cur.z, cur.w};
    float uv[4] = {up.x, up.y, up.z, up.w};
    float dv[4] = {dn.x, dn.y, dn.z, dn.w};
    #pragma unroll
    for (int j = 0; j < 4; ++j) {
        float v = cv[j];
        bool el = (j > 0) || hl, er = (j < 3) || hr;
        float vl = (j > 0) ? cv[j - 1] : lft;
        float vr = (j < 3) ? cv[j + 1] : rgt;
        float nmn = fminf(fminf(el ? vl : BIGF, er ? vr : BIGF),
                          fminf(hu ? uv[j] : BIGF, hd ? dv[j] : BIGF));
        float nmx = fmaxf(fmaxf(el ? vl : -BIGF, er ? vr : -BIGF),
                          fmaxf(hu ? uv[j] : -BIGF, hd ? dv[j] : -BIGF));
        mnf[j] = (v <= nmn);
        mxf[j] = (v >= nmx);
        if (WANTK) kk[j] = f2key(cv[j]);
    }
}

// ---------------- K1: two-pass scan, one atomic pair per wave ----------------
__global__ __launch_bounds__(256) void topo_scan2_kernel(
        const float* __restrict__ X, const float* __restrict__ Y,
        uint32_t* __restrict__ gkeys, uint32_t* __restrict__ gcnt, int B) {
    const int tid = threadIdx.x;
    const int lane = tid & 63;
    const int wv = tid >> 6;
    const int gw = blockIdx.x * 4 + wv;      // 0..8191: wave id
    const int im = gw >> 4;                  // image id (16 waves/image)
    const int r0 = (gw & 15) * 16;           // first of this wave's 16 rows
    const float* img = ((im & 1) ? Y : X) + (size_t)(im >> 1) * NPIX;
    const unsigned long long ltm = (1ull << lane) - 1ull;

    // ---- pass A: count extrema in my 16 rows ----
    uint32_t cMin = 0, cMax = 0;
    for (int it = 0; it < 16; ++it) {
        bool mnf[4], mxf[4]; uint32_t kk[4];
        stencilRow<false>(img, r0 + it, lane, mnf, mxf, kk);
        cMin += (uint32_t)__popcll(__ballot(mnf[0])) + (uint32_t)__popcll(__ballot(mnf[1]))
              + (uint32_t)__popcll(__ballot(mnf[2])) + (uint32_t)__popcll(__ballot(mnf[3]));
        cMax += (uint32_t)__popcll(__ballot(mxf[0])) + (uint32_t)__popcll(__ballot(mxf[1]))
              + (uint32_t)__popcll(__ballot(mxf[2])) + (uint32_t)__popcll(__ballot(mxf[3]));
    }

    // ---- reserve global list space: one independent atomic pair per wave ----
    uint32_t bMin = 0, bMax = 0;
    if (lane == 0) {
        bMin = atomicAdd(&gcnt[im * 2 + 0], cMin);
        bMax = atomicAdd(&gcnt[im * 2 + 1], cMax);
    }
    bMin = __shfl(bMin, 0);
    bMax = __shfl(bMax, 0);
    uint32_t* dMin = gkeys + (size_t)(im * 2 + 0) * LCAP;
    uint32_t* dMax = gkeys + (size_t)(im * 2 + 1) * LCAP;

    // ---- pass B: recompute (L2-hit) and write at known offsets ----
    for (int it = 0; it < 16; ++it) {
        bool mnf[4], mxf[4]; uint32_t kk[4];
        stencilRow<true>(img, r0 + it, lane, mnf, mxf, kk);
        {
            unsigned long long m0 = __ballot(mnf[0]), m1 = __ballot(mnf[1]),
                               m2 = __ballot(mnf[2]), m3 = __ballot(mnf[3]);
            uint32_t c0 = (uint32_t)__popcll(m0), c1 = (uint32_t)__popcll(m1),
                     c2 = (uint32_t)__popcll(m2), c3 = (uint32_t)__popcll(m3);
            uint32_t o;
            if (mnf[0]) { o = bMin + (uint32_t)__popcll(m0 & ltm);                dMin[o < LCAP ? o : LCAP - 1] = kk[0]; }
            if (mnf[1]) { o = bMin + c0 + (uint32_t)__popcll(m1 & ltm);           dMin[o < LCAP ? o : LCAP - 1] = kk[1]; }
            if (mnf[2]) { o = bMin + c0 + c1 + (uint32_t)__popcll(m2 & ltm);      dMin[o < LCAP ? o : LCAP - 1] = kk[2]; }
            if (mnf[3]) { o = bMin + c0 + c1 + c2 + (uint32_t)__popcll(m3 & ltm); dMin[o < LCAP ? o : LCAP - 1] = kk[3]; }
            bMin += c0 + c1 + c2 + c3;
        }
        {
            unsigned long long m0 = __ballot(mxf[0]), m1 = __ballot(mxf[1]),
                               m2 = __ballot(mxf[2]), m3 = __ballot(mxf[3]);
            uint32_t c0 = (uint32_t)__popcll(m0), c1 = (uint32_t)__popcll(m1),
                     c2 = (uint32_t)__popcll(m2), c3 = (uint32_t)__popcll(m3);
            uint32_t o;
            if (mxf[0]) { o = bMax + (uint32_t)__popcll(m0 & ltm);                dMax[o < LCAP ? o : LCAP - 1] = kk[0]; }
            if (mxf[1]) { o = bMax + c0 + (uint32_t)__popcll(m1 & ltm);           dMax[o < LCAP ? o : LCAP - 1] = kk[1]; }
            if (mxf[2]) { o = bMax + c0 + c1 + (uint32_t)__popcll(m2 & ltm);      dMax[o < LCAP ? o : LCAP - 1] = kk[2]; }
            if (mxf[3]) { o = bMax + c0 + c1 + c2 + (uint32_t)__popcll(m3 & ltm); dMax[o < LCAP ? o : LCAP - 1] = kk[3]; }
            bMax += c0 + c1 + c2 + c3;
        }
    }
}

// ---------------- K2: per-image radix select + register sort ----------------
struct SMQ {
    uint32_t keys[LCAP];      // 64 KB
    uint32_t h8[8 * HPAD];    // 8.25 KB (skewed copies)
    uint32_t pref[2], rank[2], ccnt[2];
    int      flagAll[2];
    float    buf[4][KPTS];    // 2 KB
};                            // ~74.5 KB -> 2 blocks/CU

__device__ __forceinline__ void binSelP(const uint32_t* h, int ncop, int lane, uint32_t r,
                                        uint32_t& bsel, uint32_t& newr) {
    uint32_t b0 = 0, b1 = 0, b2 = 0, b3 = 0;
    for (int c = 0; c < ncop; ++c) {
        const uint32_t* hh = h + c * HPAD;
        b0 += hh[4 * lane];     b1 += hh[4 * lane + 1];
        b2 += hh[4 * lane + 2]; b3 += hh[4 * lane + 3];
    }
    uint32_t s4 = b0 + b1 + b2 + b3, cum = s4;
    #pragma unroll
    for (int d = 1; d < 64; d <<= 1) { uint32_t t = __shfl_up(cum, d); if (lane >= d) cum += t; }
    unsigned long long m = __ballot(cum > r);
    int L = (m == 0ull) ? 63 : __builtin_ctzll(m);
    uint32_t cumL = __shfl(cum, L), s4L = __shfl(s4, L);
    uint32_t a0 = __shfl(b0, L), a1 = __shfl(b1, L), a2 = __shfl(b2, L);
    uint32_t excl = cumL - s4L;
    if (excl + a0 > r)                { bsel = 4u * L;     newr = r - excl; }
    else if (excl + a0 + a1 > r)      { bsel = 4u * L + 1; newr = r - excl - a0; }
    else if (excl + a0 + a1 + a2 > r) { bsel = 4u * L + 2; newr = r - excl - a0 - a1; }
    else                              { bsel = 4u * L + 3; newr = r - excl - a0 - a1 - a2; }
}

// 128-element bitonic sort in registers, one wave, 2 elems/lane.
__device__ __forceinline__ void waveSort128(float e[2], bool asc, int lane) {
    for (int size = 2; size <= 128; size <<= 1) {
        for (int stride = size >> 1; stride > 0; stride >>= 1) {
            if (stride == 64) {
                float a = e[0], b = e[1];
                e[0] = asc ? fminf(a, b) : fmaxf(a, b);
                e[1] = asc ? fmaxf(a, b) : fminf(a, b);
            } else {
                #pragma unroll
                for (int r = 0; r < 2; ++r) {
                    int i = r * 64 + lane;
                    float v = e[r];
                    float w = __shfl_xor(v, stride);
                    bool up = ((i & size) == 0) ? asc : !asc;
                    bool lower = (i & stride) == 0;
                    float mn = fminf(v, w), mx = fmaxf(v, w);
                    e[r] = (lower == up) ? mn : mx;
                }
            }
        }
    }
}

__global__ __launch_bounds__(NTH, 8) void topo_sel_kernel(
        const uint32_t* __restrict__ gkeys, const uint32_t* __restrict__ gcnt,
        float* __restrict__ diagOut, int B) {
    __shared__ SMQ sm;
    const int tid = threadIdx.x;
    const int lane = tid & 63;
    const int wv = tid >> 6;
    const int im = blockIdx.x;
    const int hc = lane & 7;

    for (int ph = 0; ph < 2; ++ph) {   // 0: minima -> {b0,d1}; 1: maxima -> {d0,b1}
        for (int i = tid; i < 8 * HPAD; i += NTH) sm.h8[i] = 0u;
        __syncthreads();
        const uint32_t* list = gkeys + (size_t)(im * 2 + ph) * LCAP;
        uint32_t C = gcnt[im * 2 + ph]; if (C > LCAP) C = LCAP;

        for (uint32_t i = tid; i < C; i += NTH) {
            uint32_t k = list[i];
            sm.keys[i] = k;
            atomicAdd(&sm.h8[hc * HPAD + (k >> 24)], 1u);
        }
        __syncthreads();

        if (wv < 2) {
            bool low = (wv == 0);
            if (C < KPTS) {
                if (lane == 0) { sm.flagAll[wv] = 1; sm.pref[wv] = 0u; sm.rank[wv] = 0u; }
            } else {
                uint32_t bsel, nr;
                binSelP(sm.h8, 8, lane, low ? (KPTS - 1) : (C - KPTS), bsel, nr);
                if (lane == 0) { sm.flagAll[wv] = 0; sm.pref[wv] = bsel; sm.rank[wv] = nr; }
            }
        }
        __syncthreads();

        for (int lvl = 2; lvl >= 0; --lvl) {
            for (int i = tid; i < 2 * HPAD; i += NTH) sm.h8[i] = 0u;
            __syncthreads();
            int f0 = sm.flagAll[0], f1 = sm.flagAll[1];
            uint32_t p0 = sm.pref[0], p1 = sm.pref[1];
            const int sp = 8 * (lvl + 1), sb = 8 * lvl;
            for (uint32_t i = tid; i < C; i += NTH) {
                uint32_t k = sm.keys[i], hi = k >> sp, by = (k >> sb) & 255u;
                if (!f0 && hi == p0) atomicAdd(&sm.h8[by], 1u);
                if (!f1 && hi == p1) atomicAdd(&sm.h8[HPAD + by], 1u);
            }
            __syncthreads();
            if (wv < 2 && !sm.flagAll[wv]) {
                uint32_t bsel, nr;
                binSelP(&sm.h8[wv * HPAD], 1, lane, sm.rank[wv], bsel, nr);
                if (lane == 0) { sm.pref[wv] = (sm.pref[wv] << 8) | bsel; sm.rank[wv] = nr; }
            }
            __syncthreads();
        }

        if (tid < 2) sm.ccnt[tid] = 0u;
        __syncthreads();
        const int g0 = (ph == 0) ? 0 : 1;
        const int g1 = (ph == 0) ? 3 : 2;
        {
            int f0 = sm.flagAll[0], f1 = sm.flagAll[1];
            uint32_t t0 = sm.pref[0], t1 = sm.pref[1];
            for (uint32_t i = tid; i < C; i += NTH) {
                uint32_t k = sm.keys[i];
                if (f0 || k < t0) { uint32_t s = atomicAdd(&sm.ccnt[0], 1u); if (s < KPTS) sm.buf[g0][s] = key2f(k); }
                if (f1 || k > t1) { uint32_t s = atomicAdd(&sm.ccnt[1], 1u); if (s < KPTS) sm.buf[g1][s] = key2f(k); }
            }
        }
        __syncthreads();
        if (tid < 2 * KPTS) {
            int l = tid >> 7, i = tid & 127;
            int g = (l == 0) ? g0 : g1;
            if ((uint32_t)i >= sm.ccnt[l])
                sm.buf[g][i] = sm.flagAll[l] ? ((l == 0) ? BIGF : -BIGF) : key2f(sm.pref[l]);
        }
        __syncthreads();
    }

    if (wv < 4) {
        float e[2];
        e[0] = sm.buf[wv][lane];
        e[1] = sm.buf[wv][lane + 64];
        waveSort128(e, wv < 2, lane);
        diagOut[(size_t)im * 512 + wv * 128 + lane]      = e[0];
        diagOut[(size_t)im * 512 + wv * 128 + 64 + lane] = e[1];
    }
}

// ---------------- loss + reduce ----------------
__global__ __launch_bounds__(128) void topo_loss_kernel(
        const float* __restrict__ diag, float* __restrict__ lossOut, int B) {
    const int s = blockIdx.x, i = threadIdx.x;
    const float* xw = diag + (size_t)(2 * s) * 512;
    const float* yw = xw + 512;
    const float H = 0.5f * BIGF;
    float b0x = xw[i], d0x = xw[128 + i], b1x = xw[256 + i], d1x = xw[384 + i];
    float b0y = yw[i], d0y = yw[128 + i], b1y = yw[256 + i], d1y = yw[384 + i];
    bool vx0 = (b0x < H) && (d0x < H);
    float px0b = vx0 ? b0x : 0.f, px0d = vx0 ? fmaxf(d0x, b0x) : 0.f;
    bool vy0 = (b0y < H) && (d0y < H);
    float py0b = vy0 ? b0y : 0.f, py0d = vy0 ? fmaxf(d0y, b0y) : 0.f;
    bool vx1 = (b1x > -H) && (d1x > -H);
    float px1b = vx1 ? b1x : 0.f, px1d = vx1 ? fminf(d1x, b1x) : 0.f;
    bool vy1 = (b1y > -H) && (d1y > -H);
    float py1b = vy1 ? b1y : 0.f, py1d = vy1 ? fminf(d1y, b1y) : 0.f;
    float e0 = px0b - py0b, e1 = px0d - py0d, e2 = px1b - py1b, e3 = px1d - py1d;
    float total = e0 * e0 + e1 * e1 + e2 * e2 + e3 * e3;
    for (int off = 32; off; off >>= 1) total += __shfl_down(total, off);
    __shared__ float lr[2];
    if ((i & 63) == 0) lr[i >> 6] = total;
    __syncthreads();
    if (i == 0) lossOut[s] = lr[0] + lr[1];
}

__global__ void topo_reduce_kernel(const float* __restrict__ ws, float* __restrict__ out, int B) {
    float v = 0.f;
    for (int i = threadIdx.x; i < B; i += 256) v += ws[i];
    __shared__ float r[4];
    for (int off = 32; off; off >>= 1) v += __shfl_down(v, off);
    if ((threadIdx.x & 63) == 0) r[threadIdx.x >> 6] = v;
    __syncthreads();
    if (threadIdx.x == 0) out[0] = (r[0] + r[1] + r[2] + r[3]) / (float)B;
}

// ================= fallback: round-8/9 fused pd3 kernel =================
struct SMP {
    uint32_t keys[LCAP];
    uint32_t h8[8][256];
    uint32_t cnt[2];
    uint32_t pref[2], rank[2], ccnt[2];
    int      flagAll[2];
    float    buf[4][KPTS];
};

__device__ __forceinline__ void binSelN(const uint32_t (*h)[256], int ncop, int lane, uint32_t r,
                                        uint32_t& bsel, uint32_t& newr) {
    uint32_t b0 = 0, b1 = 0, b2 = 0, b3 = 0;
    for (int c = 0; c < ncop; ++c) {
        b0 += h[c][4 * lane];     b1 += h[c][4 * lane + 1];
        b2 += h[c][4 * lane + 2]; b3 += h[c][4 * lane + 3];
    }
    uint32_t s4 = b0 + b1 + b2 + b3, cum = s4;
    #pragma unroll
    for (int d = 1; d < 64; d <<= 1) { uint32_t t = __shfl_up(cum, d); if (lane >= d) cum += t; }
    unsigned long long m = __ballot(cum > r);
    int L = (m == 0ull) ? 63 : __builtin_ctzll(m);
    uint32_t cumL = __shfl(cum, L), s4L = __shfl(s4, L);
    uint32_t a0 = __shfl(b0, L), a1 = __shfl(b1, L), a2 = __shfl(b2, L);
    uint32_t excl = cumL - s4L;
    if (excl + a0 > r)                { bsel = 4u * L;     newr = r - excl; }
    else if (excl + a0 + a1 > r)      { bsel = 4u * L + 1; newr = r - excl - a0; }
    else if (excl + a0 + a1 + a2 > r) { bsel = 4u * L + 2; newr = r - excl - a0 - a1; }
    else                              { bsel = 4u * L + 3; newr = r - excl - a0 - a1 - a2; }
}

__global__ __launch_bounds__(NTH, 8) void topo_pd3_kernel(
        const float* __restrict__ X, const float* __restrict__ Y,
        float* __restrict__ diagOut, int B) {
    __shared__ SMP sm;
    const int tid = threadIdx.x;
    const int lane = tid & 63;
    const int wv = tid >> 6;
    const int bid = blockIdx.x;
    const float* img = ((bid & 1) ? Y : X) + (size_t)(bid >> 1) * NPIX;
    const unsigned long long ltm = (1ull << lane) - 1ull;

    for (int ph = 0; ph < 2; ++ph) {
        for (int i = tid; i < 8 * 256; i += NTH) ((uint32_t*)sm.h8)[i] = 0u;
        if (tid == 0) sm.cnt[0] = 0u;
        __syncthreads();
        for (int it = 0; it < QITERS; ++it) {
            int q = it * NTH + tid;
            int p = q * 4;
            int row = p >> 8;
            bool mnf[4], mxf[4]; uint32_t kk[4];
            stencilRow<true>(img, row, lane, mnf, mxf, kk);
            bool e0 = (ph == 0) ? mnf[0] : mxf[0], e1 = (ph == 0) ? mnf[1] : mxf[1];
            bool e2 = (ph == 0) ? mnf[2] : mxf[2], e3 = (ph == 0) ? mnf[3] : mxf[3];
            unsigned long long m0 = __ballot(e0), m1 = __ballot(e1),
                               m2 = __ballot(e2), m3 = __ballot(e3);
            uint32_t c0 = (uint32_t)__popcll(m0), c1 = (uint32_t)__popcll(m1),
                     c2 = (uint32_t)__popcll(m2), c3 = (uint32_t)__popcll(m3);
            uint32_t base = 0;
            if (lane == 0) base = atomicAdd(&sm.cnt[0], c0 + c1 + c2 + c3);
            base = __shfl(base, 0);
            uint32_t o;
            if (e0) { o = base + (uint32_t)__popcll(m0 & ltm);                sm.keys[o < LCAP ? o : LCAP - 1] = kk[0]; atomicAdd(&sm.h8[wv >> 1][kk[0] >> 24], 1u); }
            if (e1) { o = base + c0 + (uint32_t)__popcll(m1 & ltm);           sm.keys[o < LCAP ? o : LCAP - 1] = kk[1]; atomicAdd(&sm.h8[wv >> 1][kk[1] >> 24], 1u); }
            if (e2) { o = base + c0 + c1 + (uint32_t)__popcll(m2 & ltm);      sm.keys[o < LCAP ? o : LCAP - 1] = kk[2]; atomicAdd(&sm.h8[wv >> 1][kk[2] >> 24], 1u); }
            if (e3) { o = base + c0 + c1 + c2 + (uint32_t)__popcll(m3 & ltm); sm.keys[o < LCAP ? o : LCAP - 1] = kk[3]; atomicAdd(&sm.h8[wv >> 1][kk[3] >> 24], 1u); }
        }
        __syncthreads();
        uint32_t C = sm.cnt[0]; if (C > LCAP) C = LCAP;

        if (wv < 2) {
            bool low = (wv == 0);
            if (C < KPTS) {
                if (lane == 0) { sm.flagAll[wv] = 1; sm.pref[wv] = 0u; sm.rank[wv] = 0u; }
            } else {
                uint32_t bsel, nr;
                binSelN(sm.h8, 8, lane, low ? (KPTS - 1) : (C - KPTS), bsel, nr);
                if (lane == 0) { sm.flagAll[wv] = 0; sm.pref[wv] = bsel; sm.rank[wv] = nr; }
            }
        }
        __syncthreads();

        for (int lvl = 2; lvl >= 0; --lvl) {
            for (int i = tid; i < 2 * 256; i += NTH) ((uint32_t*)sm.h8)[i] = 0u;
            __syncthreads();
            int f0 = sm.flagAll[0], f1 = sm.flagAll[1];
            uint32_t p0 = sm.pref[0], p1 = sm.pref[1];
            const int sp = 8 * (lvl + 1), sb = 8 * lvl;
            for (uint32_t i = tid; i < C; i += NTH) {
                uint32_t k = sm.keys[i], hi = k >> sp, by = (k >> sb) & 255u;
                if (!f0 && hi == p0) atomicAdd(&sm.h8[0][by], 1u);
                if (!f1 && hi == p1) atomicAdd(&sm.h8[1][by], 1u);
            }
            __syncthreads();
            if (wv < 2 && !sm.flagAll[wv]) {
                uint32_t bsel, nr;
                binSelN((const uint32_t(*)[256])&sm.h8[wv], 1, lane, sm.rank[wv], bsel, nr);
                if (lane == 0) { sm.pref[wv] = (sm.pref[wv] << 8) | bsel; sm.rank[wv] = nr; }
            }
            __syncthreads();
        }

        if (tid < 2) sm.ccnt[tid] = 0u;
        __syncthreads();
        const int g0 = (ph == 0) ? 0 : 1;
        const int g1 = (ph == 0) ? 3 : 2;
        {
            int f0 = sm.flagAll[0], f1 = sm.flagAll[1];
            uint32_t t0 = sm.pref[0], t1 = sm.pref[1];
            for (uint32_t i = tid; i < C; i += NTH) {
                uint32_t k = sm.keys[i];
                if (f0 || k < t0) { uint32_t s = atomicAdd(&sm.ccnt[0], 1u); if (s < KPTS) sm.buf[g0][s] = key2f(k); }
                if (f1 || k > t1) { uint32_t s = atomicAdd(&sm.ccnt[1], 1u); if (s < KPTS) sm.buf[g1][s] = key2f(k); }
            }
        }
        __syncthreads();
        if (tid < 2 * KPTS) {
            int l = tid >> 7, i = tid & 127;
            int g = (l == 0) ? g0 : g1;
            if ((uint32_t)i >= sm.ccnt[l])
                sm.buf[g][i] = sm.flagAll[l] ? ((l == 0) ? BIGF : -BIGF) : key2f(sm.pref[l]);
        }
        __syncthreads();
    }

    if (wv < 4) {
        float e[2];
        e[0] = sm.buf[wv][lane];
        e[1] = sm.buf[wv][lane + 64];
        waveSort128(e, wv < 2, lane);
        diagOut[(size_t)bid * 512 + wv * 128 + lane]      = e[0];
        diagOut[(size_t)bid * 512 + wv * 128 + 64 + lane] = e[1];
    }
}

extern "C" void kernel_launch(void* const* d_in, const int* in_sizes, int n_in,
                              void* d_out, int out_size, void* d_ws, size_t ws_size,
                              hipStream_t stream) {
    const float* X = (const float*)d_in[0];
    const float* Y = (const float*)d_in[1];
    float* out = (float*)d_out;
    const int B = in_sizes[0] / NPIX;   // 256 samples

    size_t diagSz = (size_t)2 * B * 512 * sizeof(float);          // 2 MB
    size_t lossSz = (size_t)B * sizeof(float);
    size_t cntSz  = (size_t)2 * B * 2 * sizeof(uint32_t);         // 4 KB
    size_t keysSz = (size_t)2 * B * 2 * LCAP * sizeof(uint32_t);  // 67 MB

    if (ws_size >= diagSz + lossSz + cntSz + keysSz) {
        float* diag = (float*)d_ws;
        float* lossbuf = (float*)((char*)d_ws + diagSz);
        uint32_t* gcnt = (uint32_t*)((char*)d_ws + diagSz + lossSz);
        uint32_t* gkeys = (uint32_t*)((char*)d_ws + diagSz + lossSz + cntSz);
        hipMemsetAsync(gcnt, 0, cntSz, stream);
        topo_scan2_kernel<<<2048, 256, 0, stream>>>(X, Y, gkeys, gcnt, B);
        topo_sel_kernel<<<2 * B, NTH, 0, stream>>>(gkeys, gcnt, diag, B);
        topo_loss_kernel<<<B, 128, 0, stream>>>(diag, lossbuf, B);
        topo_reduce_kernel<<<1, 256, 0, stream>>>(lossbuf, out, B);
    } else if (ws_size >= diagSz + lossSz) {
        float* diag = (float*)d_ws;
        float* lossbuf = (float*)((char*)d_ws + diagSz);
        topo_pd3_kernel<<<2 * B, NTH, 0, stream>>>(X, Y, diag, B);
        topo_loss_kernel<<<B, 128, 0, stream>>>(diag, lossbuf, B);
        topo_reduce_kernel<<<1, 256, 0, stream>>>(lossbuf, out, B);
    } else {
        topo_pd3_kernel<<<2 * B, NTH, 0, stream>>>(X, Y, (float*)d_ws, B);
    }
}

// Round 14
// 94.100 us; speedup vs baseline: 3.7256x; 1.3053x over previous
//
#include <hip/hip_runtime.h>
#include <stdint.h>

// TopoLoss: approximate persistence-diagram Wasserstein loss.
// Round 14: round-13 design (single-pass segmented scan, zero atomics) with the
// host-side gcnt16 allocation bug fixed: the count array is 2B images x 2 types
// x 16 segments = 64 KB; round 13 allocated half, so counts for images >= 256
// overflowed into gkeys and corrupted the lists. Kernels unchanged.
// Order statistics bit-exact.

#define KPTS 128
#define BIGF 1.0e9f
#define IMG_W 256
#define NPIX (IMG_W * IMG_W)
#define NTH 1024
#define QITERS (NPIX / 4 / NTH)   // fallback kernel
#define SEGC 1024                 // per-wave segment capacity (E~819, sigma~26: +8sig)
#define LCAP (16 * SEGC)          // 16384 per image-type
#define HPAD 264                  // histogram copy stride (bank-skew: 264%32=8)

__device__ __forceinline__ uint32_t f2key(float f) {
    uint32_t u = __float_as_uint(f);
    return (u & 0x80000000u) ? ~u : (u | 0x80000000u);
}
__device__ __forceinline__ float key2f(uint32_t k) {
    uint32_t u = (k & 0x80000000u) ? (k ^ 0x80000000u) : ~k;
    return __uint_as_float(u);
}

// buf layout: 0=b0 (min,low,asc) 1=d0 (max,low,asc) 2=b1 (max,high,desc) 3=d1 (min,high,desc)

// ---- shared stencil: one image row per wave, 4 px/lane, halo via shfl ----
template <bool WANTK>
__device__ __forceinline__ void stencilRow(const float* __restrict__ img, int row, int lane,
                                           bool mnf[4], bool mxf[4], uint32_t kk[4]) {
    const float* base = img + (size_t)row * IMG_W;
    float4 cur = *(const float4*)(base + lane * 4);
    bool hu = row > 0, hd = row < (IMG_W - 1);
    float4 up = cur, dn = cur;
    if (hu) up = *(const float4*)(base - IMG_W + lane * 4);
    if (hd) dn = *(const float4*)(base + IMG_W + lane * 4);
    float lft = __shfl_up(cur.w, 1);
    float rgt = __shfl_down(cur.x, 1);
    bool hl = (lane > 0), hr = (lane < 63);
    float cv[4] = {cur.x, cur.y, cur.z, cur.w};
    float uv[4] = {up.x, up.y, up.z, up.w};
    float dv[4] = {dn.x, dn.y, dn.z, dn.w};
    #pragma unroll
    for (int j = 0; j < 4; ++j) {
        float v = cv[j];
        bool el = (j > 0) || hl, er = (j < 3) || hr;
        float vl = (j > 0) ? cv[j - 1] : lft;
        float vr = (j < 3) ? cv[j + 1] : rgt;
        float nmn = fminf(fminf(el ? vl : BIGF, er ? vr : BIGF),
                          fminf(hu ? uv[j] : BIGF, hd ? dv[j] : BIGF));
        float nmx = fmaxf(fmaxf(el ? vl : -BIGF, er ? vr : -BIGF),
                          fmaxf(hu ? uv[j] : -BIGF, hd ? dv[j] : -BIGF));
        mnf[j] = (v <= nmn);
        mxf[j] = (v >= nmx);
        if (WANTK) kk[j] = f2key(cv[j]);
    }
}

// ---------------- K1: single-pass scan, segmented output, zero atomics ----------------
__global__ __launch_bounds__(256) void topo_scan3_kernel(
        const float* __restrict__ X, const float* __restrict__ Y,
        uint32_t* __restrict__ gkeys, uint32_t* __restrict__ gcnt16, int B) {
    const int tid = threadIdx.x;
    const int lane = tid & 63;
    const int wv = tid >> 6;
    const int gw = blockIdx.x * 4 + wv;      // 0..2B*16-1
    const int im = gw >> 4;                  // image id (16 waves/image)
    const int seg = gw & 15;                 // my segment
    const int r0 = seg * 16;                 // my 16 rows
    const float* img = ((im & 1) ? Y : X) + (size_t)(im >> 1) * NPIX;
    const unsigned long long ltm = (1ull << lane) - 1ull;

    uint32_t* dMin = gkeys + (size_t)(im * 2 + 0) * LCAP + seg * SEGC;
    uint32_t* dMax = gkeys + (size_t)(im * 2 + 1) * LCAP + seg * SEGC;
    uint32_t cMin = 0, cMax = 0;

    for (int it = 0; it < 16; ++it) {
        bool mnf[4], mxf[4]; uint32_t kk[4];
        stencilRow<true>(img, r0 + it, lane, mnf, mxf, kk);
        {
            unsigned long long m0 = __ballot(mnf[0]), m1 = __ballot(mnf[1]),
                               m2 = __ballot(mnf[2]), m3 = __ballot(mnf[3]);
            uint32_t c0 = (uint32_t)__popcll(m0), c1 = (uint32_t)__popcll(m1),
                     c2 = (uint32_t)__popcll(m2), c3 = (uint32_t)__popcll(m3);
            uint32_t o;
            if (mnf[0]) { o = cMin + (uint32_t)__popcll(m0 & ltm);                if (o < SEGC) dMin[o] = kk[0]; }
            if (mnf[1]) { o = cMin + c0 + (uint32_t)__popcll(m1 & ltm);           if (o < SEGC) dMin[o] = kk[1]; }
            if (mnf[2]) { o = cMin + c0 + c1 + (uint32_t)__popcll(m2 & ltm);      if (o < SEGC) dMin[o] = kk[2]; }
            if (mnf[3]) { o = cMin + c0 + c1 + c2 + (uint32_t)__popcll(m3 & ltm); if (o < SEGC) dMin[o] = kk[3]; }
            cMin += c0 + c1 + c2 + c3;
        }
        {
            unsigned long long m0 = __ballot(mxf[0]), m1 = __ballot(mxf[1]),
                               m2 = __ballot(mxf[2]), m3 = __ballot(mxf[3]);
            uint32_t c0 = (uint32_t)__popcll(m0), c1 = (uint32_t)__popcll(m1),
                     c2 = (uint32_t)__popcll(m2), c3 = (uint32_t)__popcll(m3);
            uint32_t o;
            if (mxf[0]) { o = cMax + (uint32_t)__popcll(m0 & ltm);                if (o < SEGC) dMax[o] = kk[0]; }
            if (mxf[1]) { o = cMax + c0 + (uint32_t)__popcll(m1 & ltm);           if (o < SEGC) dMax[o] = kk[1]; }
            if (mxf[2]) { o = cMax + c0 + c1 + (uint32_t)__popcll(m2 & ltm);      if (o < SEGC) dMax[o] = kk[2]; }
            if (mxf[3]) { o = cMax + c0 + c1 + c2 + (uint32_t)__popcll(m3 & ltm); if (o < SEGC) dMax[o] = kk[3]; }
            cMax += c0 + c1 + c2 + c3;
        }
    }
    if (lane == 0) {
        gcnt16[(im * 2 + 0) * 16 + seg] = (cMin < SEGC) ? cMin : SEGC;
        gcnt16[(im * 2 + 1) * 16 + seg] = (cMax < SEGC) ? cMax : SEGC;
    }
}

// ---------------- K2: segment-compacting radix select + register sort ----------------
struct SMQ {
    uint32_t keys[LCAP];      // 64 KB
    uint32_t h8[8 * HPAD];    // 8.25 KB (skewed copies)
    uint32_t pref[2], rank[2], ccnt[2];
    int      flagAll[2];
    float    buf[4][KPTS];    // 2 KB
};                            // ~74.5 KB -> 2 blocks/CU

__device__ __forceinline__ void binSelP(const uint32_t* h, int ncop, int lane, uint32_t r,
                                        uint32_t& bsel, uint32_t& newr) {
    uint32_t b0 = 0, b1 = 0, b2 = 0, b3 = 0;
    for (int c = 0; c < ncop; ++c) {
        const uint32_t* hh = h + c * HPAD;
        b0 += hh[4 * lane];     b1 += hh[4 * lane + 1];
        b2 += hh[4 * lane + 2]; b3 += hh[4 * lane + 3];
    }
    uint32_t s4 = b0 + b1 + b2 + b3, cum = s4;
    #pragma unroll
    for (int d = 1; d < 64; d <<= 1) { uint32_t t = __shfl_up(cum, d); if (lane >= d) cum += t; }
    unsigned long long m = __ballot(cum > r);
    int L = (m == 0ull) ? 63 : __builtin_ctzll(m);
    uint32_t cumL = __shfl(cum, L), s4L = __shfl(s4, L);
    uint32_t a0 = __shfl(b0, L), a1 = __shfl(b1, L), a2 = __shfl(b2, L);
    uint32_t excl = cumL - s4L;
    if (excl + a0 > r)                { bsel = 4u * L;     newr = r - excl; }
    else if (excl + a0 + a1 > r)      { bsel = 4u * L + 1; newr = r - excl - a0; }
    else if (excl + a0 + a1 + a2 > r) { bsel = 4u * L + 2; newr = r - excl - a0 - a1; }
    else                              { bsel = 4u * L + 3; newr = r - excl - a0 - a1 - a2; }
}

// 128-element bitonic sort in registers, one wave, 2 elems/lane.
__device__ __forceinline__ void waveSort128(float e[2], bool asc, int lane) {
    for (int size = 2; size <= 128; size <<= 1) {
        for (int stride = size >> 1; stride > 0; stride >>= 1) {
            if (stride == 64) {
                float a = e[0], b = e[1];
                e[0] = asc ? fminf(a, b) : fmaxf(a, b);
                e[1] = asc ? fmaxf(a, b) : fminf(a, b);
            } else {
                #pragma unroll
                for (int r = 0; r < 2; ++r) {
                    int i = r * 64 + lane;
                    float v = e[r];
                    float w = __shfl_xor(v, stride);
                    bool up = ((i & size) == 0) ? asc : !asc;
                    bool lower = (i & stride) == 0;
                    float mn = fminf(v, w), mx = fmaxf(v, w);
                    e[r] = (lower == up) ? mn : mx;
                }
            }
        }
    }
}

__global__ __launch_bounds__(NTH, 8) void topo_sel2_kernel(
        const uint32_t* __restrict__ gkeys, const uint32_t* __restrict__ gcnt16,
        float* __restrict__ diagOut, int B) {
    __shared__ SMQ sm;
    const int tid = threadIdx.x;
    const int lane = tid & 63;
    const int wv = tid >> 6;        // 16 waves
    const int im = blockIdx.x;
    const int hc = lane & 7;

    for (int ph = 0; ph < 2; ++ph) {   // 0: minima -> {b0,d1}; 1: maxima -> {d0,b1}
        for (int i = tid; i < 8 * HPAD; i += NTH) sm.h8[i] = 0u;
        __syncthreads();
        const uint32_t* list = gkeys + (size_t)(im * 2 + ph) * LCAP;
        const uint32_t* cnts = gcnt16 + (im * 2 + ph) * 16;

        // every wave: read 16 segment counts, shfl prefix scan -> my offset / total
        uint32_t cw = (lane < 16) ? cnts[lane] : 0;
        uint32_t inc = cw;
        #pragma unroll
        for (int d = 1; d < 16; d <<= 1) { uint32_t t = __shfl_up(inc, d); if (lane >= d) inc += t; }
        uint32_t C = __shfl(inc, 15);                 // total count
        uint32_t myCnt = __shfl(cw, wv);              // my segment's count
        uint32_t myOff = __shfl(inc, wv) - myCnt;     // exclusive prefix

        // wave wv compacts segment wv into LDS (+ lane-privatized skewed MSB hist)
        for (uint32_t i = lane; i < myCnt; i += 64) {
            uint32_t k = list[wv * SEGC + i];
            sm.keys[myOff + i] = k;
            atomicAdd(&sm.h8[hc * HPAD + (k >> 24)], 1u);
        }
        __syncthreads();

        // top-level select: wave0 = low sel, wave1 = high sel
        if (wv < 2) {
            bool low = (wv == 0);
            if (C < KPTS) {
                if (lane == 0) { sm.flagAll[wv] = 1; sm.pref[wv] = 0u; sm.rank[wv] = 0u; }
            } else {
                uint32_t bsel, nr;
                binSelP(sm.h8, 8, lane, low ? (KPTS - 1) : (C - KPTS), bsel, nr);
                if (lane == 0) { sm.flagAll[wv] = 0; sm.pref[wv] = bsel; sm.rank[wv] = nr; }
            }
        }
        __syncthreads();

        // levels 2..0: prefix-filtered LDS list scans
        for (int lvl = 2; lvl >= 0; --lvl) {
            for (int i = tid; i < 2 * HPAD; i += NTH) sm.h8[i] = 0u;
            __syncthreads();
            int f0 = sm.flagAll[0], f1 = sm.flagAll[1];
            uint32_t p0 = sm.pref[0], p1 = sm.pref[1];
            const int sp = 8 * (lvl + 1), sb = 8 * lvl;
            for (uint32_t i = tid; i < C; i += NTH) {
                uint32_t k = sm.keys[i], hi = k >> sp, by = (k >> sb) & 255u;
                if (!f0 && hi == p0) atomicAdd(&sm.h8[by], 1u);
                if (!f1 && hi == p1) atomicAdd(&sm.h8[HPAD + by], 1u);
            }
            __syncthreads();
            if (wv < 2 && !sm.flagAll[wv]) {
                uint32_t bsel, nr;
                binSelP(&sm.h8[wv * HPAD], 1, lane, sm.rank[wv], bsel, nr);
                if (lane == 0) { sm.pref[wv] = (sm.pref[wv] << 8) | bsel; sm.rank[wv] = nr; }
            }
            __syncthreads();
        }

        // collect strict winners, tie/sentinel pad
        if (tid < 2) sm.ccnt[tid] = 0u;
        __syncthreads();
        const int g0 = (ph == 0) ? 0 : 1;
        const int g1 = (ph == 0) ? 3 : 2;
        {
            int f0 = sm.flagAll[0], f1 = sm.flagAll[1];
            uint32_t t0 = sm.pref[0], t1 = sm.pref[1];
            for (uint32_t i = tid; i < C; i += NTH) {
                uint32_t k = sm.keys[i];
                if (f0 || k < t0) { uint32_t s = atomicAdd(&sm.ccnt[0], 1u); if (s < KPTS) sm.buf[g0][s] = key2f(k); }
                if (f1 || k > t1) { uint32_t s = atomicAdd(&sm.ccnt[1], 1u); if (s < KPTS) sm.buf[g1][s] = key2f(k); }
            }
        }
        __syncthreads();
        if (tid < 2 * KPTS) {
            int l = tid >> 7, i = tid & 127;
            int g = (l == 0) ? g0 : g1;
            if ((uint32_t)i >= sm.ccnt[l])
                sm.buf[g][i] = sm.flagAll[l] ? ((l == 0) ? BIGF : -BIGF) : key2f(sm.pref[l]);
        }
        __syncthreads();
    }

    // 4 register-resident 128-elem bitonic sorts (waves 0..3, no barriers)
    if (wv < 4) {
        float e[2];
        e[0] = sm.buf[wv][lane];
        e[1] = sm.buf[wv][lane + 64];
        waveSort128(e, wv < 2, lane);
        diagOut[(size_t)im * 512 + wv * 128 + lane]      = e[0];
        diagOut[(size_t)im * 512 + wv * 128 + 64 + lane] = e[1];
    }
}

// ---------------- loss + reduce ----------------
__global__ __launch_bounds__(128) void topo_loss_kernel(
        const float* __restrict__ diag, float* __restrict__ lossOut, int B) {
    const int s = blockIdx.x, i = threadIdx.x;
    const float* xw = diag + (size_t)(2 * s) * 512;
    const float* yw = xw + 512;
    const float H = 0.5f * BIGF;
    float b0x = xw[i], d0x = xw[128 + i], b1x = xw[256 + i], d1x = xw[384 + i];
    float b0y = yw[i], d0y = yw[128 + i], b1y = yw[256 + i], d1y = yw[384 + i];
    bool vx0 = (b0x < H) && (d0x < H);
    float px0b = vx0 ? b0x : 0.f, px0d = vx0 ? fmaxf(d0x, b0x) : 0.f;
    bool vy0 = (b0y < H) && (d0y < H);
    float py0b = vy0 ? b0y : 0.f, py0d = vy0 ? fmaxf(d0y, b0y) : 0.f;
    bool vx1 = (b1x > -H) && (d1x > -H);
    float px1b = vx1 ? b1x : 0.f, px1d = vx1 ? fminf(d1x, b1x) : 0.f;
    bool vy1 = (b1y > -H) && (d1y > -H);
    float py1b = vy1 ? b1y : 0.f, py1d = vy1 ? fminf(d1y, b1y) : 0.f;
    float e0 = px0b - py0b, e1 = px0d - py0d, e2 = px1b - py1b, e3 = px1d - py1d;
    float total = e0 * e0 + e1 * e1 + e2 * e2 + e3 * e3;
    for (int off = 32; off; off >>= 1) total += __shfl_down(total, off);
    __shared__ float lr[2];
    if ((i & 63) == 0) lr[i >> 6] = total;
    __syncthreads();
    if (i == 0) lossOut[s] = lr[0] + lr[1];
}

__global__ void topo_reduce_kernel(const float* __restrict__ ws, float* __restrict__ out, int B) {
    float v = 0.f;
    for (int i = threadIdx.x; i < B; i += 256) v += ws[i];
    __shared__ float r[4];
    for (int off = 32; off; off >>= 1) v += __shfl_down(v, off);
    if ((threadIdx.x & 63) == 0) r[threadIdx.x >> 6] = v;
    __syncthreads();
    if (threadIdx.x == 0) out[0] = (r[0] + r[1] + r[2] + r[3]) / (float)B;
}

// ================= fallback: fused pd3 kernel (round-8/9 proven) =================
struct SMP {
    uint32_t keys[LCAP];
    uint32_t h8[8][256];
    uint32_t cnt[2];
    uint32_t pref[2], rank[2], ccnt[2];
    int      flagAll[2];
    float    buf[4][KPTS];
};

__device__ __forceinline__ void binSelN(const uint32_t (*h)[256], int ncop, int lane, uint32_t r,
                                        uint32_t& bsel, uint32_t& newr) {
    uint32_t b0 = 0, b1 = 0, b2 = 0, b3 = 0;
    for (int c = 0; c < ncop; ++c) {
        b0 += h[c][4 * lane];     b1 += h[c][4 * lane + 1];
        b2 += h[c][4 * lane + 2]; b3 += h[c][4 * lane + 3];
    }
    uint32_t s4 = b0 + b1 + b2 + b3, cum = s4;
    #pragma unroll
    for (int d = 1; d < 64; d <<= 1) { uint32_t t = __shfl_up(cum, d); if (lane >= d) cum += t; }
    unsigned long long m = __ballot(cum > r);
    int L = (m == 0ull) ? 63 : __builtin_ctzll(m);
    uint32_t cumL = __shfl(cum, L), s4L = __shfl(s4, L);
    uint32_t a0 = __shfl(b0, L), a1 = __shfl(b1, L), a2 = __shfl(b2, L);
    uint32_t excl = cumL - s4L;
    if (excl + a0 > r)                { bsel = 4u * L;     newr = r - excl; }
    else if (excl + a0 + a1 > r)      { bsel = 4u * L + 1; newr = r - excl - a0; }
    else if (excl + a0 + a1 + a2 > r) { bsel = 4u * L + 2; newr = r - excl - a0 - a1; }
    else                              { bsel = 4u * L + 3; newr = r - excl - a0 - a1 - a2; }
}

__global__ __launch_bounds__(NTH, 8) void topo_pd3_kernel(
        const float* __restrict__ X, const float* __restrict__ Y,
        float* __restrict__ diagOut, int B) {
    __shared__ SMP sm;
    const int tid = threadIdx.x;
    const int lane = tid & 63;
    const int wv = tid >> 6;
    const int bid = blockIdx.x;
    const float* img = ((bid & 1) ? Y : X) + (size_t)(bid >> 1) * NPIX;
    const unsigned long long ltm = (1ull << lane) - 1ull;

    for (int ph = 0; ph < 2; ++ph) {
        for (int i = tid; i < 8 * 256; i += NTH) ((uint32_t*)sm.h8)[i] = 0u;
        if (tid == 0) sm.cnt[0] = 0u;
        __syncthreads();
        for (int it = 0; it < QITERS; ++it) {
            int q = it * NTH + tid;
            int p = q * 4;
            int row = p >> 8;
            bool mnf[4], mxf[4]; uint32_t kk[4];
            stencilRow<true>(img, row, lane, mnf, mxf, kk);
            bool e0 = (ph == 0) ? mnf[0] : mxf[0], e1 = (ph == 0) ? mnf[1] : mxf[1];
            bool e2 = (ph == 0) ? mnf[2] : mxf[2], e3 = (ph == 0) ? mnf[3] : mxf[3];
            unsigned long long m0 = __ballot(e0), m1 = __ballot(e1),
                               m2 = __ballot(e2), m3 = __ballot(e3);
            uint32_t c0 = (uint32_t)__popcll(m0), c1 = (uint32_t)__popcll(m1),
                     c2 = (uint32_t)__popcll(m2), c3 = (uint32_t)__popcll(m3);
            uint32_t base = 0;
            if (lane == 0) base = atomicAdd(&sm.cnt[0], c0 + c1 + c2 + c3);
            base = __shfl(base, 0);
            uint32_t o;
            if (e0) { o = base + (uint32_t)__popcll(m0 & ltm);                sm.keys[o < LCAP ? o : LCAP - 1] = kk[0]; atomicAdd(&sm.h8[wv >> 1][kk[0] >> 24], 1u); }
            if (e1) { o = base + c0 + (uint32_t)__popcll(m1 & ltm);           sm.keys[o < LCAP ? o : LCAP - 1] = kk[1]; atomicAdd(&sm.h8[wv >> 1][kk[1] >> 24], 1u); }
            if (e2) { o = base + c0 + c1 + (uint32_t)__popcll(m2 & ltm);      sm.keys[o < LCAP ? o : LCAP - 1] = kk[2]; atomicAdd(&sm.h8[wv >> 1][kk[2] >> 24], 1u); }
            if (e3) { o = base + c0 + c1 + c2 + (uint32_t)__popcll(m3 & ltm); sm.keys[o < LCAP ? o : LCAP - 1] = kk[3]; atomicAdd(&sm.h8[wv >> 1][kk[3] >> 24], 1u); }
        }
        __syncthreads();
        uint32_t C = sm.cnt[0]; if (C > LCAP) C = LCAP;

        if (wv < 2) {
            bool low = (wv == 0);
            if (C < KPTS) {
                if (lane == 0) { sm.flagAll[wv] = 1; sm.pref[wv] = 0u; sm.rank[wv] = 0u; }
            } else {
                uint32_t bsel, nr;
                binSelN(sm.h8, 8, lane, low ? (KPTS - 1) : (C - KPTS), bsel, nr);
                if (lane == 0) { sm.flagAll[wv] = 0; sm.pref[wv] = bsel; sm.rank[wv] = nr; }
            }
        }
        __syncthreads();

        for (int lvl = 2; lvl >= 0; --lvl) {
            for (int i = tid; i < 2 * 256; i += NTH) ((uint32_t*)sm.h8)[i] = 0u;
            __syncthreads();
            int f0 = sm.flagAll[0], f1 = sm.flagAll[1];
            uint32_t p0 = sm.pref[0], p1 = sm.pref[1];
            const int sp = 8 * (lvl + 1), sb = 8 * lvl;
            for (uint32_t i = tid; i < C; i += NTH) {
                uint32_t k = sm.keys[i], hi = k >> sp, by = (k >> sb) & 255u;
                if (!f0 && hi == p0) atomicAdd(&sm.h8[0][by], 1u);
                if (!f1 && hi == p1) atomicAdd(&sm.h8[1][by], 1u);
            }
            __syncthreads();
            if (wv < 2 && !sm.flagAll[wv]) {
                uint32_t bsel, nr;
                binSelN((const uint32_t(*)[256])&sm.h8[wv], 1, lane, sm.rank[wv], bsel, nr);
                if (lane == 0) { sm.pref[wv] = (sm.pref[wv] << 8) | bsel; sm.rank[wv] = nr; }
            }
            __syncthreads();
        }

        if (tid < 2) sm.ccnt[tid] = 0u;
        __syncthreads();
        const int g0 = (ph == 0) ? 0 : 1;
        const int g1 = (ph == 0) ? 3 : 2;
        {
            int f0 = sm.flagAll[0], f1 = sm.flagAll[1];
            uint32_t t0 = sm.pref[0], t1 = sm.pref[1];
            for (uint32_t i = tid; i < C; i += NTH) {
                uint32_t k = sm.keys[i];
                if (f0 || k < t0) { uint32_t s = atomicAdd(&sm.ccnt[0], 1u); if (s < KPTS) sm.buf[g0][s] = key2f(k); }
                if (f1 || k > t1) { uint32_t s = atomicAdd(&sm.ccnt[1], 1u); if (s < KPTS) sm.buf[g1][s] = key2f(k); }
            }
        }
        __syncthreads();
        if (tid < 2 * KPTS) {
            int l = tid >> 7, i = tid & 127;
            int g = (l == 0) ? g0 : g1;
            if ((uint32_t)i >= sm.ccnt[l])
                sm.buf[g][i] = sm.flagAll[l] ? ((l == 0) ? BIGF : -BIGF) : key2f(sm.pref[l]);
        }
        __syncthreads();
    }

    if (wv < 4) {
        float e[2];
        e[0] = sm.buf[wv][lane];
        e[1] = sm.buf[wv][lane + 64];
        waveSort128(e, wv < 2, lane);
        diagOut[(size_t)bid * 512 + wv * 128 + lane]      = e[0];
        diagOut[(size_t)bid * 512 + wv * 128 + 64 + lane] = e[1];
    }
}

extern "C" void kernel_launch(void* const* d_in, const int* in_sizes, int n_in,
                              void* d_out, int out_size, void* d_ws, size_t ws_size,
                              hipStream_t stream) {
    const float* X = (const float*)d_in[0];
    const float* Y = (const float*)d_in[1];
    float* out = (float*)d_out;
    const int B = in_sizes[0] / NPIX;   // 256 samples

    size_t diagSz = (size_t)2 * B * 512 * sizeof(float);              // 2 MB
    size_t lossSz = (size_t)B * sizeof(float);
    size_t cntSz  = (size_t)2 * B * 2 * 16 * sizeof(uint32_t);        // 64 KB (2B imgs x 2 types x 16 segs) -- r13 bug: was half
    size_t keysSz = (size_t)2 * B * 2 * LCAP * sizeof(uint32_t);      // 67 MB

    if (ws_size >= diagSz + lossSz + cntSz + keysSz) {
        float* diag = (float*)d_ws;
        float* lossbuf = (float*)((char*)d_ws + diagSz);
        uint32_t* gcnt16 = (uint32_t*)((char*)d_ws + diagSz + lossSz);
        uint32_t* gkeys = (uint32_t*)((char*)d_ws + diagSz + lossSz + cntSz);
        // no memset needed: every segment count is written unconditionally
        topo_scan3_kernel<<<8 * B, 256, 0, stream>>>(X, Y, gkeys, gcnt16, B);
        topo_sel2_kernel<<<2 * B, NTH, 0, stream>>>(gkeys, gcnt16, diag, B);
        topo_loss_kernel<<<B, 128, 0, stream>>>(diag, lossbuf, B);
        topo_reduce_kernel<<<1, 256, 0, stream>>>(lossbuf, out, B);
    } else if (ws_size >= diagSz + lossSz) {
        float* diag = (float*)d_ws;
        float* lossbuf = (float*)((char*)d_ws + diagSz);
        topo_pd3_kernel<<<2 * B, NTH, 0, stream>>>(X, Y, diag, B);
        topo_loss_kernel<<<B, 128, 0, stream>>>(diag, lossbuf, B);
        topo_reduce_kernel<<<1, 256, 0, stream>>>(lossbuf, out, B);
    } else {
        topo_pd3_kernel<<<2 * B, NTH, 0, stream>>>(X, Y, (float*)d_ws, B);
    }
}

// Round 15
// 90.317 us; speedup vs baseline: 3.8816x; 1.0419x over previous
//
#include <hip/hip_runtime.h>
#include <stdint.h>

// TopoLoss: approximate persistence-diagram Wasserstein loss.
// Round 15: scan kernel rewritten with a rolling 3-row register window:
// one new row load per iteration (vs 3), issued ahead of the stencil compute
// (explicit software pipeline; r14's VGPR=24 showed the compiler wasn't
// pipelining). Segmented zero-atomic output + proven sel/loss/reduce unchanged.
// Order statistics bit-exact.

#define KPTS 128
#define BIGF 1.0e9f
#define IMG_W 256
#define NPIX (IMG_W * IMG_W)
#define NTH 1024
#define QITERS (NPIX / 4 / NTH)   // fallback kernel
#define SEGC 1024                 // per-wave segment capacity (E~819, sigma~26: +8sig)
#define LCAP (16 * SEGC)          // 16384 per image-type
#define HPAD 264                  // histogram copy stride (bank-skew: 264%32=8)

__device__ __forceinline__ uint32_t f2key(float f) {
    uint32_t u = __float_as_uint(f);
    return (u & 0x80000000u) ? ~u : (u | 0x80000000u);
}
__device__ __forceinline__ float key2f(uint32_t k) {
    uint32_t u = (k & 0x80000000u) ? (k ^ 0x80000000u) : ~k;
    return __uint_as_float(u);
}

// buf layout: 0=b0 (min,low,asc) 1=d0 (max,low,asc) 2=b1 (max,high,desc) 3=d1 (min,high,desc)

// ---- shared stencil (fallback path): one image row per wave, 4 px/lane ----
template <bool WANTK>
__device__ __forceinline__ void stencilRow(const float* __restrict__ img, int row, int lane,
                                           bool mnf[4], bool mxf[4], uint32_t kk[4]) {
    const float* base = img + (size_t)row * IMG_W;
    float4 cur = *(const float4*)(base + lane * 4);
    bool hu = row > 0, hd = row < (IMG_W - 1);
    float4 up = cur, dn = cur;
    if (hu) up = *(const float4*)(base - IMG_W + lane * 4);
    if (hd) dn = *(const float4*)(base + IMG_W + lane * 4);
    float lft = __shfl_up(cur.w, 1);
    float rgt = __shfl_down(cur.x, 1);
    bool hl = (lane > 0), hr = (lane < 63);
    float cv[4] = {cur.x, cur.y, cur.z, cur.w};
    float uv[4] = {up.x, up.y, up.z, up.w};
    float dv[4] = {dn.x, dn.y, dn.z, dn.w};
    #pragma unroll
    for (int j = 0; j < 4; ++j) {
        float v = cv[j];
        bool el = (j > 0) || hl, er = (j < 3) || hr;
        float vl = (j > 0) ? cv[j - 1] : lft;
        float vr = (j < 3) ? cv[j + 1] : rgt;
        float nmn = fminf(fminf(el ? vl : BIGF, er ? vr : BIGF),
                          fminf(hu ? uv[j] : BIGF, hd ? dv[j] : BIGF));
        float nmx = fmaxf(fmaxf(el ? vl : -BIGF, er ? vr : -BIGF),
                          fmaxf(hu ? uv[j] : -BIGF, hd ? dv[j] : -BIGF));
        mnf[j] = (v <= nmn);
        mxf[j] = (v >= nmx);
        if (WANTK) kk[j] = f2key(cv[j]);
    }
}

// ---------------- K1: rolling-window scan, segmented output, zero atomics ----------------
__global__ __launch_bounds__(256) void topo_scan4_kernel(
        const float* __restrict__ X, const float* __restrict__ Y,
        uint32_t* __restrict__ gkeys, uint32_t* __restrict__ gcnt16, int B) {
    const int tid = threadIdx.x;
    const int lane = tid & 63;
    const int wv = tid >> 6;
    const int gw = blockIdx.x * 4 + wv;      // 0..2B*16-1
    const int im = gw >> 4;                  // image id (16 waves/image)
    const int seg = gw & 15;                 // my segment
    const int r0 = seg * 16;                 // my 16 rows
    const float* img = ((im & 1) ? Y : X) + (size_t)(im >> 1) * NPIX;
    const float* base0 = img + (size_t)r0 * IMG_W + lane * 4;
    const unsigned long long ltm = (1ull << lane) - 1ull;

    uint32_t* dMin = gkeys + (size_t)(im * 2 + 0) * LCAP + seg * SEGC;
    uint32_t* dMax = gkeys + (size_t)(im * 2 + 1) * LCAP + seg * SEGC;
    uint32_t cMin = 0, cMax = 0;

    // rolling 3-row window: prev = row r-1, cur = row r, next = row r+1
    float4 cur  = *(const float4*)(base0);
    float4 prev = (r0 > 0) ? *(const float4*)(base0 - IMG_W) : cur;          // guarded by hu
    float4 next = *(const float4*)(base0 + IMG_W);                           // r0+1 <= 241 < 256 always

    for (int it = 0; it < 16; ++it) {
        const int row = r0 + it;
        const bool hu = row > 0, hd = row < (IMG_W - 1);
        // prefetch row r+2 (next iteration's 'next') BEFORE the compute
        float4 nxt2 = cur;
        if (it < 15 && row + 2 < IMG_W)
            nxt2 = *(const float4*)(base0 + (it + 2) * IMG_W);

        float lft = __shfl_up(cur.w, 1);
        float rgt = __shfl_down(cur.x, 1);
        bool hl = (lane > 0), hr = (lane < 63);
        float cv[4] = {cur.x, cur.y, cur.z, cur.w};
        float uv[4] = {prev.x, prev.y, prev.z, prev.w};
        float dv[4] = {next.x, next.y, next.z, next.w};
        bool mnf[4], mxf[4];
        uint32_t kk[4];
        #pragma unroll
        for (int j = 0; j < 4; ++j) {
            float v = cv[j];
            bool el = (j > 0) || hl, er = (j < 3) || hr;
            float vl = (j > 0) ? cv[j - 1] : lft;
            float vr = (j < 3) ? cv[j + 1] : rgt;
            float nmn = fminf(fminf(el ? vl : BIGF, er ? vr : BIGF),
                              fminf(hu ? uv[j] : BIGF, hd ? dv[j] : BIGF));
            float nmx = fmaxf(fmaxf(el ? vl : -BIGF, er ? vr : -BIGF),
                              fmaxf(hu ? uv[j] : -BIGF, hd ? dv[j] : -BIGF));
            mnf[j] = (v <= nmn);
            mxf[j] = (v >= nmx);
            kk[j] = f2key(v);
        }
        {
            unsigned long long m0 = __ballot(mnf[0]), m1 = __ballot(mnf[1]),
                               m2 = __ballot(mnf[2]), m3 = __ballot(mnf[3]);
            uint32_t c0 = (uint32_t)__popcll(m0), c1 = (uint32_t)__popcll(m1),
                     c2 = (uint32_t)__popcll(m2), c3 = (uint32_t)__popcll(m3);
            uint32_t o;
            if (mnf[0]) { o = cMin + (uint32_t)__popcll(m0 & ltm);                if (o < SEGC) dMin[o] = kk[0]; }
            if (mnf[1]) { o = cMin + c0 + (uint32_t)__popcll(m1 & ltm);           if (o < SEGC) dMin[o] = kk[1]; }
            if (mnf[2]) { o = cMin + c0 + c1 + (uint32_t)__popcll(m2 & ltm);      if (o < SEGC) dMin[o] = kk[2]; }
            if (mnf[3]) { o = cMin + c0 + c1 + c2 + (uint32_t)__popcll(m3 & ltm); if (o < SEGC) dMin[o] = kk[3]; }
            cMin += c0 + c1 + c2 + c3;
        }
        {
            unsigned long long m0 = __ballot(mxf[0]), m1 = __ballot(mxf[1]),
                               m2 = __ballot(mxf[2]), m3 = __ballot(mxf[3]);
            uint32_t c0 = (uint32_t)__popcll(m0), c1 = (uint32_t)__popcll(m1),
                     c2 = (uint32_t)__popcll(m2), c3 = (uint32_t)__popcll(m3);
            uint32_t o;
            if (mxf[0]) { o = cMax + (uint32_t)__popcll(m0 & ltm);                if (o < SEGC) dMax[o] = kk[0]; }
            if (mxf[1]) { o = cMax + c0 + (uint32_t)__popcll(m1 & ltm);           if (o < SEGC) dMax[o] = kk[1]; }
            if (mxf[2]) { o = cMax + c0 + c1 + (uint32_t)__popcll(m2 & ltm);      if (o < SEGC) dMax[o] = kk[2]; }
            if (mxf[3]) { o = cMax + c0 + c1 + c2 + (uint32_t)__popcll(m3 & ltm); if (o < SEGC) dMax[o] = kk[3]; }
            cMax += c0 + c1 + c2 + c3;
        }
        prev = cur; cur = next; next = nxt2;   // slide the window
    }
    if (lane == 0) {
        gcnt16[(im * 2 + 0) * 16 + seg] = (cMin < SEGC) ? cMin : SEGC;
        gcnt16[(im * 2 + 1) * 16 + seg] = (cMax < SEGC) ? cMax : SEGC;
    }
}

// ---------------- K2: segment-compacting radix select + register sort ----------------
struct SMQ {
    uint32_t keys[LCAP];      // 64 KB
    uint32_t h8[8 * HPAD];    // 8.25 KB (skewed copies)
    uint32_t pref[2], rank[2], ccnt[2];
    int      flagAll[2];
    float    buf[4][KPTS];    // 2 KB
};                            // ~74.5 KB -> 2 blocks/CU

__device__ __forceinline__ void binSelP(const uint32_t* h, int ncop, int lane, uint32_t r,
                                        uint32_t& bsel, uint32_t& newr) {
    uint32_t b0 = 0, b1 = 0, b2 = 0, b3 = 0;
    for (int c = 0; c < ncop; ++c) {
        const uint32_t* hh = h + c * HPAD;
        b0 += hh[4 * lane];     b1 += hh[4 * lane + 1];
        b2 += hh[4 * lane + 2]; b3 += hh[4 * lane + 3];
    }
    uint32_t s4 = b0 + b1 + b2 + b3, cum = s4;
    #pragma unroll
    for (int d = 1; d < 64; d <<= 1) { uint32_t t = __shfl_up(cum, d); if (lane >= d) cum += t; }
    unsigned long long m = __ballot(cum > r);
    int L = (m == 0ull) ? 63 : __builtin_ctzll(m);
    uint32_t cumL = __shfl(cum, L), s4L = __shfl(s4, L);
    uint32_t a0 = __shfl(b0, L), a1 = __shfl(b1, L), a2 = __shfl(b2, L);
    uint32_t excl = cumL - s4L;
    if (excl + a0 > r)                { bsel = 4u * L;     newr = r - excl; }
    else if (excl + a0 + a1 > r)      { bsel = 4u * L + 1; newr = r - excl - a0; }
    else if (excl + a0 + a1 + a2 > r) { bsel = 4u * L + 2; newr = r - excl - a0 - a1; }
    else                              { bsel = 4u * L + 3; newr = r - excl - a0 - a1 - a2; }
}

// 128-element bitonic sort in registers, one wave, 2 elems/lane.
__device__ __forceinline__ void waveSort128(float e[2], bool asc, int lane) {
    for (int size = 2; size <= 128; size <<= 1) {
        for (int stride = size >> 1; stride > 0; stride >>= 1) {
            if (stride == 64) {
                float a = e[0], b = e[1];
                e[0] = asc ? fminf(a, b) : fmaxf(a, b);
                e[1] = asc ? fmaxf(a, b) : fminf(a, b);
            } else {
                #pragma unroll
                for (int r = 0; r < 2; ++r) {
                    int i = r * 64 + lane;
                    float v = e[r];
                    float w = __shfl_xor(v, stride);
                    bool up = ((i & size) == 0) ? asc : !asc;
                    bool lower = (i & stride) == 0;
                    float mn = fminf(v, w), mx = fmaxf(v, w);
                    e[r] = (lower == up) ? mn : mx;
                }
            }
        }
    }
}

__global__ __launch_bounds__(NTH, 8) void topo_sel2_kernel(
        const uint32_t* __restrict__ gkeys, const uint32_t* __restrict__ gcnt16,
        float* __restrict__ diagOut, int B) {
    __shared__ SMQ sm;
    const int tid = threadIdx.x;
    const int lane = tid & 63;
    const int wv = tid >> 6;        // 16 waves
    const int im = blockIdx.x;
    const int hc = lane & 7;

    for (int ph = 0; ph < 2; ++ph) {   // 0: minima -> {b0,d1}; 1: maxima -> {d0,b1}
        for (int i = tid; i < 8 * HPAD; i += NTH) sm.h8[i] = 0u;
        __syncthreads();
        const uint32_t* list = gkeys + (size_t)(im * 2 + ph) * LCAP;
        const uint32_t* cnts = gcnt16 + (im * 2 + ph) * 16;

        // every wave: read 16 segment counts, shfl prefix scan -> my offset / total
        uint32_t cw = (lane < 16) ? cnts[lane] : 0;
        uint32_t inc = cw;
        #pragma unroll
        for (int d = 1; d < 16; d <<= 1) { uint32_t t = __shfl_up(inc, d); if (lane >= d) inc += t; }
        uint32_t C = __shfl(inc, 15);                 // total count
        uint32_t myCnt = __shfl(cw, wv);              // my segment's count
        uint32_t myOff = __shfl(inc, wv) - myCnt;     // exclusive prefix

        // wave wv compacts segment wv into LDS (+ lane-privatized skewed MSB hist)
        for (uint32_t i = lane; i < myCnt; i += 64) {
            uint32_t k = list[wv * SEGC + i];
            sm.keys[myOff + i] = k;
            atomicAdd(&sm.h8[hc * HPAD + (k >> 24)], 1u);
        }
        __syncthreads();

        // top-level select: wave0 = low sel, wave1 = high sel
        if (wv < 2) {
            bool low = (wv == 0);
            if (C < KPTS) {
                if (lane == 0) { sm.flagAll[wv] = 1; sm.pref[wv] = 0u; sm.rank[wv] = 0u; }
            } else {
                uint32_t bsel, nr;
                binSelP(sm.h8, 8, lane, low ? (KPTS - 1) : (C - KPTS), bsel, nr);
                if (lane == 0) { sm.flagAll[wv] = 0; sm.pref[wv] = bsel; sm.rank[wv] = nr; }
            }
        }
        __syncthreads();

        // levels 2..0: prefix-filtered LDS list scans
        for (int lvl = 2; lvl >= 0; --lvl) {
            for (int i = tid; i < 2 * HPAD; i += NTH) sm.h8[i] = 0u;
            __syncthreads();
            int f0 = sm.flagAll[0], f1 = sm.flagAll[1];
            uint32_t p0 = sm.pref[0], p1 = sm.pref[1];
            const int sp = 8 * (lvl + 1), sb = 8 * lvl;
            for (uint32_t i = tid; i < C; i += NTH) {
                uint32_t k = sm.keys[i], hi = k >> sp, by = (k >> sb) & 255u;
                if (!f0 && hi == p0) atomicAdd(&sm.h8[by], 1u);
                if (!f1 && hi == p1) atomicAdd(&sm.h8[HPAD + by], 1u);
            }
            __syncthreads();
            if (wv < 2 && !sm.flagAll[wv]) {
                uint32_t bsel, nr;
                binSelP(&sm.h8[wv * HPAD], 1, lane, sm.rank[wv], bsel, nr);
                if (lane == 0) { sm.pref[wv] = (sm.pref[wv] << 8) | bsel; sm.rank[wv] = nr; }
            }
            __syncthreads();
        }

        // collect strict winners, tie/sentinel pad
        if (tid < 2) sm.ccnt[tid] = 0u;
        __syncthreads();
        const int g0 = (ph == 0) ? 0 : 1;
        const int g1 = (ph == 0) ? 3 : 2;
        {
            int f0 = sm.flagAll[0], f1 = sm.flagAll[1];
            uint32_t t0 = sm.pref[0], t1 = sm.pref[1];
            for (uint32_t i = tid; i < C; i += NTH) {
                uint32_t k = sm.keys[i];
                if (f0 || k < t0) { uint32_t s = atomicAdd(&sm.ccnt[0], 1u); if (s < KPTS) sm.buf[g0][s] = key2f(k); }
                if (f1 || k > t1) { uint32_t s = atomicAdd(&sm.ccnt[1], 1u); if (s < KPTS) sm.buf[g1][s] = key2f(k); }
            }
        }
        __syncthreads();
        if (tid < 2 * KPTS) {
            int l = tid >> 7, i = tid & 127;
            int g = (l == 0) ? g0 : g1;
            if ((uint32_t)i >= sm.ccnt[l])
                sm.buf[g][i] = sm.flagAll[l] ? ((l == 0) ? BIGF : -BIGF) : key2f(sm.pref[l]);
        }
        __syncthreads();
    }

    // 4 register-resident 128-elem bitonic sorts (waves 0..3, no barriers)
    if (wv < 4) {
        float e[2];
        e[0] = sm.buf[wv][lane];
        e[1] = sm.buf[wv][lane + 64];
        waveSort128(e, wv < 2, lane);
        diagOut[(size_t)im * 512 + wv * 128 + lane]      = e[0];
        diagOut[(size_t)im * 512 + wv * 128 + 64 + lane] = e[1];
    }
}

// ---------------- loss + reduce ----------------
__global__ __launch_bounds__(128) void topo_loss_kernel(
        const float* __restrict__ diag, float* __restrict__ lossOut, int B) {
    const int s = blockIdx.x, i = threadIdx.x;
    const float* xw = diag + (size_t)(2 * s) * 512;
    const float* yw = xw + 512;
    const float H = 0.5f * BIGF;
    float b0x = xw[i], d0x = xw[128 + i], b1x = xw[256 + i], d1x = xw[384 + i];
    float b0y = yw[i], d0y = yw[128 + i], b1y = yw[256 + i], d1y = yw[384 + i];
    bool vx0 = (b0x < H) && (d0x < H);
    float px0b = vx0 ? b0x : 0.f, px0d = vx0 ? fmaxf(d0x, b0x) : 0.f;
    bool vy0 = (b0y < H) && (d0y < H);
    float py0b = vy0 ? b0y : 0.f, py0d = vy0 ? fmaxf(d0y, b0y) : 0.f;
    bool vx1 = (b1x > -H) && (d1x > -H);
    float px1b = vx1 ? b1x : 0.f, px1d = vx1 ? fminf(d1x, b1x) : 0.f;
    bool vy1 = (b1y > -H) && (d1y > -H);
    float py1b = vy1 ? b1y : 0.f, py1d = vy1 ? fminf(d1y, b1y) : 0.f;
    float e0 = px0b - py0b, e1 = px0d - py0d, e2 = px1b - py1b, e3 = px1d - py1d;
    float total = e0 * e0 + e1 * e1 + e2 * e2 + e3 * e3;
    for (int off = 32; off; off >>= 1) total += __shfl_down(total, off);
    __shared__ float lr[2];
    if ((i & 63) == 0) lr[i >> 6] = total;
    __syncthreads();
    if (i == 0) lossOut[s] = lr[0] + lr[1];
}

__global__ void topo_reduce_kernel(const float* __restrict__ ws, float* __restrict__ out, int B) {
    float v = 0.f;
    for (int i = threadIdx.x; i < B; i += 256) v += ws[i];
    __shared__ float r[4];
    for (int off = 32; off; off >>= 1) v += __shfl_down(v, off);
    if ((threadIdx.x & 63) == 0) r[threadIdx.x >> 6] = v;
    __syncthreads();
    if (threadIdx.x == 0) out[0] = (r[0] + r[1] + r[2] + r[3]) / (float)B;
}

// ================= fallback: fused pd3 kernel (round-8/9 proven) =================
struct SMP {
    uint32_t keys[LCAP];
    uint32_t h8[8][256];
    uint32_t cnt[2];
    uint32_t pref[2], rank[2], ccnt[2];
    int      flagAll[2];
    float    buf[4][KPTS];
};

__device__ __forceinline__ void binSelN(const uint32_t (*h)[256], int ncop, int lane, uint32_t r,
                                        uint32_t& bsel, uint32_t& newr) {
    uint32_t b0 = 0, b1 = 0, b2 = 0, b3 = 0;
    for (int c = 0; c < ncop; ++c) {
        b0 += h[c][4 * lane];     b1 += h[c][4 * lane + 1];
        b2 += h[c][4 * lane + 2]; b3 += h[c][4 * lane + 3];
    }
    uint32_t s4 = b0 + b1 + b2 + b3, cum = s4;
    #pragma unroll
    for (int d = 1; d < 64; d <<= 1) { uint32_t t = __shfl_up(cum, d); if (lane >= d) cum += t; }
    unsigned long long m = __ballot(cum > r);
    int L = (m == 0ull) ? 63 : __builtin_ctzll(m);
    uint32_t cumL = __shfl(cum, L), s4L = __shfl(s4, L);
    uint32_t a0 = __shfl(b0, L), a1 = __shfl(b1, L), a2 = __shfl(b2, L);
    uint32_t excl = cumL - s4L;
    if (excl + a0 > r)                { bsel = 4u * L;     newr = r - excl; }
    else if (excl + a0 + a1 > r)      { bsel = 4u * L + 1; newr = r - excl - a0; }
    else if (excl + a0 + a1 + a2 > r) { bsel = 4u * L + 2; newr = r - excl - a0 - a1; }
    else                              { bsel = 4u * L + 3; newr = r - excl - a0 - a1 - a2; }
}

__global__ __launch_bounds__(NTH, 8) void topo_pd3_kernel(
        const float* __restrict__ X, const float* __restrict__ Y,
        float* __restrict__ diagOut, int B) {
    __shared__ SMP sm;
    const int tid = threadIdx.x;
    const int lane = tid & 63;
    const int wv = tid >> 6;
    const int bid = blockIdx.x;
    const float* img = ((bid & 1) ? Y : X) + (size_t)(bid >> 1) * NPIX;
    const unsigned long long ltm = (1ull << lane) - 1ull;

    for (int ph = 0; ph < 2; ++ph) {
        for (int i = tid; i < 8 * 256; i += NTH) ((uint32_t*)sm.h8)[i] = 0u;
        if (tid == 0) sm.cnt[0] = 0u;
        __syncthreads();
        for (int it = 0; it < QITERS; ++it) {
            int q = it * NTH + tid;
            int p = q * 4;
            int row = p >> 8;
            bool mnf[4], mxf[4]; uint32_t kk[4];
            stencilRow<true>(img, row, lane, mnf, mxf, kk);
            bool e0 = (ph == 0) ? mnf[0] : mxf[0], e1 = (ph == 0) ? mnf[1] : mxf[1];
            bool e2 = (ph == 0) ? mnf[2] : mxf[2], e3 = (ph == 0) ? mnf[3] : mxf[3];
            unsigned long long m0 = __ballot(e0), m1 = __ballot(e1),
                               m2 = __ballot(e2), m3 = __ballot(e3);
            uint32_t c0 = (uint32_t)__popcll(m0), c1 = (uint32_t)__popcll(m1),
                     c2 = (uint32_t)__popcll(m2), c3 = (uint32_t)__popcll(m3);
            uint32_t base = 0;
            if (lane == 0) base = atomicAdd(&sm.cnt[0], c0 + c1 + c2 + c3);
            base = __shfl(base, 0);
            uint32_t o;
            if (e0) { o = base + (uint32_t)__popcll(m0 & ltm);                sm.keys[o < LCAP ? o : LCAP - 1] = kk[0]; atomicAdd(&sm.h8[wv >> 1][kk[0] >> 24], 1u); }
            if (e1) { o = base + c0 + (uint32_t)__popcll(m1 & ltm);           sm.keys[o < LCAP ? o : LCAP - 1] = kk[1]; atomicAdd(&sm.h8[wv >> 1][kk[1] >> 24], 1u); }
            if (e2) { o = base + c0 + c1 + (uint32_t)__popcll(m2 & ltm);      sm.keys[o < LCAP ? o : LCAP - 1] = kk[2]; atomicAdd(&sm.h8[wv >> 1][kk[2] >> 24], 1u); }
            if (e3) { o = base + c0 + c1 + c2 + (uint32_t)__popcll(m3 & ltm); sm.keys[o < LCAP ? o : LCAP - 1] = kk[3]; atomicAdd(&sm.h8[wv >> 1][kk[3] >> 24], 1u); }
        }
        __syncthreads();
        uint32_t C = sm.cnt[0]; if (C > LCAP) C = LCAP;

        if (wv < 2) {
            bool low = (wv == 0);
            if (C < KPTS) {
                if (lane == 0) { sm.flagAll[wv] = 1; sm.pref[wv] = 0u; sm.rank[wv] = 0u; }
            } else {
                uint32_t bsel, nr;
                binSelN(sm.h8, 8, lane, low ? (KPTS - 1) : (C - KPTS), bsel, nr);
                if (lane == 0) { sm.flagAll[wv] = 0; sm.pref[wv] = bsel; sm.rank[wv] = nr; }
            }
        }
        __syncthreads();

        for (int lvl = 2; lvl >= 0; --lvl) {
            for (int i = tid; i < 2 * 256; i += NTH) ((uint32_t*)sm.h8)[i] = 0u;
            __syncthreads();
            int f0 = sm.flagAll[0], f1 = sm.flagAll[1];
            uint32_t p0 = sm.pref[0], p1 = sm.pref[1];
            const int sp = 8 * (lvl + 1), sb = 8 * lvl;
            for (uint32_t i = tid; i < C; i += NTH) {
                uint32_t k = sm.keys[i], hi = k >> sp, by = (k >> sb) & 255u;
                if (!f0 && hi == p0) atomicAdd(&sm.h8[0][by], 1u);
                if (!f1 && hi == p1) atomicAdd(&sm.h8[1][by], 1u);
            }
            __syncthreads();
            if (wv < 2 && !sm.flagAll[wv]) {
                uint32_t bsel, nr;
                binSelN((const uint32_t(*)[256])&sm.h8[wv], 1, lane, sm.rank[wv], bsel, nr);
                if (lane == 0) { sm.pref[wv] = (sm.pref[wv] << 8) | bsel; sm.rank[wv] = nr; }
            }
            __syncthreads();
        }

        if (tid < 2) sm.ccnt[tid] = 0u;
        __syncthreads();
        const int g0 = (ph == 0) ? 0 : 1;
        const int g1 = (ph == 0) ? 3 : 2;
        {
            int f0 = sm.flagAll[0], f1 = sm.flagAll[1];
            uint32_t t0 = sm.pref[0], t1 = sm.pref[1];
            for (uint32_t i = tid; i < C; i += NTH) {
                uint32_t k = sm.keys[i];
                if (f0 || k < t0) { uint32_t s = atomicAdd(&sm.ccnt[0], 1u); if (s < KPTS) sm.buf[g0][s] = key2f(k); }
                if (f1 || k > t1) { uint32_t s = atomicAdd(&sm.ccnt[1], 1u); if (s < KPTS) sm.buf[g1][s] = key2f(k); }
            }
        }
        __syncthreads();
        if (tid < 2 * KPTS) {
            int l = tid >> 7, i = tid & 127;
            int g = (l == 0) ? g0 : g1;
            if ((uint32_t)i >= sm.ccnt[l])
                sm.buf[g][i] = sm.flagAll[l] ? ((l == 0) ? BIGF : -BIGF) : key2f(sm.pref[l]);
        }
        __syncthreads();
    }

    if (wv < 4) {
        float e[2];
        e[0] = sm.buf[wv][lane];
        e[1] = sm.buf[wv][lane + 64];
        waveSort128(e, wv < 2, lane);
        diagOut[(size_t)bid * 512 + wv * 128 + lane]      = e[0];
        diagOut[(size_t)bid * 512 + wv * 128 + 64 + lane] = e[1];
    }
}

extern "C" void kernel_launch(void* const* d_in, const int* in_sizes, int n_in,
                              void* d_out, int out_size, void* d_ws, size_t ws_size,
                              hipStream_t stream) {
    const float* X = (const float*)d_in[0];
    const float* Y = (const float*)d_in[1];
    float* out = (float*)d_out;
    const int B = in_sizes[0] / NPIX;   // 256 samples

    size_t diagSz = (size_t)2 * B * 512 * sizeof(float);              // 2 MB
    size_t lossSz = (size_t)B * sizeof(float);
    size_t cntSz  = (size_t)2 * B * 2 * 16 * sizeof(uint32_t);        // 64 KB (2B imgs x 2 types x 16 segs)
    size_t keysSz = (size_t)2 * B * 2 * LCAP * sizeof(uint32_t);      // 67 MB

    if (ws_size >= diagSz + lossSz + cntSz + keysSz) {
        float* diag = (float*)d_ws;
        float* lossbuf = (float*)((char*)d_ws + diagSz);
        uint32_t* gcnt16 = (uint32_t*)((char*)d_ws + diagSz + lossSz);
        uint32_t* gkeys = (uint32_t*)((char*)d_ws + diagSz + lossSz + cntSz);
        // no memset needed: every segment count is written unconditionally
        topo_scan4_kernel<<<8 * B, 256, 0, stream>>>(X, Y, gkeys, gcnt16, B);
        topo_sel2_kernel<<<2 * B, NTH, 0, stream>>>(gkeys, gcnt16, diag, B);
        topo_loss_kernel<<<B, 128, 0, stream>>>(diag, lossbuf, B);
        topo_reduce_kernel<<<1, 256, 0, stream>>>(lossbuf, out, B);
    } else if (ws_size >= diagSz + lossSz) {
        float* diag = (float*)d_ws;
        float* lossbuf = (float*)((char*)d_ws + diagSz);
        topo_pd3_kernel<<<2 * B, NTH, 0, stream>>>(X, Y, diag, B);
        topo_loss_kernel<<<B, 128, 0, stream>>>(diag, lossbuf, B);
        topo_reduce_kernel<<<1, 256, 0, stream>>>(lossbuf, out, B);
    } else {
        topo_pd3_kernel<<<2 * B, NTH, 0, stream>>>(X, Y, (float*)d_ws, B);
    }
}